// Round 16
// baseline (187.588 us; speedup 1.0000x reference)
//
#include <hip/hip_runtime.h>
#include <hip/hip_bf16.h>

#define EPS 1e-5f
#define FLASH_SMEM 72704

typedef short bf16x8 __attribute__((ext_vector_type(8)));
typedef float f32x4 __attribute__((ext_vector_type(4)));

#define GL16(gp, lp) __builtin_amdgcn_global_load_lds( \
    (const __attribute__((address_space(1))) void*)(gp), \
    (__attribute__((address_space(3))) void*)(lp), 16, 0, 0)

__device__ __forceinline__ unsigned short f2bf(float f) {
  union { float f; unsigned u; } v; v.f = f;
  return (unsigned short)((v.u + 0x7FFFu + ((v.u >> 16) & 1u)) >> 16);
}
__device__ __forceinline__ float bf2f(unsigned short u) {
  return __uint_as_float(((unsigned)u) << 16);
}

// ---------------- merged prep: 4 weight transposes + frac stats in one launch ----------------
__global__ void prep_kernel(const float* __restrict__ W0, const float* __restrict__ W1,
                            const float* __restrict__ W2, const float* __restrict__ W3,
                            unsigned short* __restrict__ T0, unsigned short* __restrict__ T1,
                            unsigned short* __restrict__ T2, unsigned short* __restrict__ T3,
                            const float* __restrict__ frac, float* __restrict__ fstats) {
  __shared__ float tile[32][33];
  const int L = blockIdx.x;
  if (L < 1024) {
    // weight transpose: z = L>>8, tiles 16x16
    int z = L >> 8, rem = L & 255;
    const float* W = z == 0 ? W0 : z == 1 ? W1 : z == 2 ? W2 : W3;
    unsigned short* Wt = z == 0 ? T0 : z == 1 ? T1 : z == 2 ? T2 : T3;
    float scale = (z == 0) ? 0.125f : 1.0f;
    int n0 = (rem & 15) * 32, k0 = (rem >> 4) * 32;
    int c = threadIdx.x & 31, r0 = threadIdx.x >> 5;
    #pragma unroll
    for (int rr = 0; rr < 32; rr += 8)
      tile[r0 + rr][c] = W[(k0 + r0 + rr) * 512 + n0 + c];
    __syncthreads();
    #pragma unroll
    for (int rr = 0; rr < 32; rr += 8)
      Wt[(n0 + r0 + rr) * 512 + k0 + c] = f2bf(tile[c][r0 + rr] * scale);
  } else {
    // frac stats: 2048 blocks x 4 waves
    int wid = (int)(((L - 1024) * 256 + threadIdx.x) >> 6);
    int ln = threadIdx.x & 63;
    int b = wid >> 10, q = wid & 1023;
    const float* fr = frac + b * 1024;
    float fq = fr[q];
    float sp = 0.f, sn = 0.f, sp2 = 0.f, sn2 = 0.f;
    for (int i = ln; i < 1024; i += 64) {
      float f = fr[i];
      float dm = (f - fq) * (fq * f);
      float p = fmaxf(dm, 0.f), nn = fminf(dm, 0.f);
      sp += p; sn += nn; sp2 += p * p; sn2 += nn * nn;
    }
    #pragma unroll
    for (int m = 32; m; m >>= 1) {
      sp += __shfl_xor(sp, m); sn += __shfl_xor(sn, m);
      sp2 += __shfl_xor(sp2, m); sn2 += __shfl_xor(sn2, m);
    }
    if (ln == 0) {
      float4 o; o.x = sp; o.y = sn; o.z = sp2; o.w = sn2;
      *(float4*)(fstats + (size_t)wid * 4) = o;
    }
  }
}

// ---------------- fused QKV GEMM: 128-row tiles, XCD panel swizzle, loadA distance-2 ----------------
__global__ __launch_bounds__(256) void qkv_gemm_kernel(
    const float* __restrict__ Aq, const float* __restrict__ Ak, const float* __restrict__ Av,
    const unsigned short* __restrict__ WqT, const unsigned short* __restrict__ WkT,
    const unsigned short* __restrict__ WvT,
    const float* __restrict__ bq, const float* __restrict__ bk, const float* __restrict__ bv,
    unsigned short* __restrict__ Qh, unsigned short* __restrict__ Kh,
    unsigned short* __restrict__ Ktr, unsigned short* __restrict__ Vt) {
  __shared__ unsigned short Al[2][128 * 32];
  __shared__ unsigned short Bl[2][128 * 32];
  const int L = blockIdx.x;
  const int xcd = L & 7, sl = L >> 3;
  const int xb = sl & 3;
  const int P = (sl >> 2) * 8 + xcd;   // panel id 0..191
  const int yb = P & 63, z = P >> 6;

  const float* A = z == 0 ? Aq : z == 1 ? Ak : Av;
  const unsigned short* Bt = z == 0 ? WqT : z == 1 ? WkT : WvT;
  const float* bias = z == 0 ? bq : z == 1 ? bk : bv;
  const float bscale = (z == 0) ? 0.125f : 1.0f;

  const int tid = threadIdx.x, ln = tid & 63, wv = tid >> 6;
  const int m0 = yb * 128, n0 = xb * 128;
  const int wr = wv >> 1, wc = wv & 1;
  const int arow = tid >> 1;
  const int agh = (tid & 1) * 2;

  auto stageB = [&](int kt, int buf) {
    int kb = kt * 32;
    #pragma unroll
    for (int u = 0; u < 2; ++u) {
      int n = tid + u * 256;
      int Lrow = n >> 2, kcs = n & 3;
      int kc = kcs ^ (Lrow & 3);
      GL16(Bt + (size_t)(n0 + Lrow) * 512 + kb + kc * 8, &Bl[buf][n * 8]);
    }
  };
  auto loadA = [&](int kt, float4* la) {
    const float* src = A + (size_t)(m0 + arow) * 512 + kt * 32 + agh * 8;
    la[0] = *(const float4*)(src);
    la[1] = *(const float4*)(src + 4);
    la[2] = *(const float4*)(src + 8);
    la[3] = *(const float4*)(src + 12);
  };
  auto writeA = [&](int buf, const float4* la) {
    #pragma unroll
    for (int G = 0; G < 2; ++G) {
      union { bf16x8 v; unsigned short u[8]; } pk;
      float4 a = la[2 * G], b2 = la[2 * G + 1];
      pk.u[0] = f2bf(a.x); pk.u[1] = f2bf(a.y); pk.u[2] = f2bf(a.z); pk.u[3] = f2bf(a.w);
      pk.u[4] = f2bf(b2.x); pk.u[5] = f2bf(b2.y); pk.u[6] = f2bf(b2.z); pk.u[7] = f2bf(b2.w);
      int dg = (agh + G) ^ (arow & 3);
      *(bf16x8*)(&Al[buf][arow * 32 + dg * 8]) = pk.v;
    }
  };

  f32x4 acc[4][4] = {};
  float4 laA[4], laB[4];
  loadA(0, laA); writeA(0, laA);   // tile 0 staged
  loadA(1, laB);                   // tile 1 in flight (distance-2 pipeline)
  stageB(0, 0);
  for (int kt = 0; kt < 16; ++kt) {
    __syncthreads();
    if (kt < 15) stageB(kt + 1, (kt + 1) & 1);
    if (kt < 14) loadA(kt + 2, (kt & 1) ? laB : laA);   // prefetch 2 ahead
    const unsigned short* a_ = Al[kt & 1];
    const unsigned short* b_ = Bl[kt & 1];
    const int kc = ln >> 4;
    bf16x8 afr[4], bfr[4];
    #pragma unroll
    for (int m = 0; m < 4; ++m) {
      int r = wr * 64 + m * 16 + (ln & 15);
      afr[m] = *(const bf16x8*)(a_ + r * 32 + ((kc ^ (r & 3)) * 8));
    }
    #pragma unroll
    for (int n = 0; n < 4; ++n) {
      int r = wc * 64 + n * 16 + (ln & 15);
      bfr[n] = *(const bf16x8*)(b_ + r * 32 + ((kc ^ (r & 3)) * 8));
    }
    #pragma unroll
    for (int m = 0; m < 4; ++m)
      #pragma unroll
      for (int n = 0; n < 4; ++n)
        acc[m][n] = __builtin_amdgcn_mfma_f32_16x16x32_bf16(afr[m], bfr[n], acc[m][n], 0, 0, 0);
    if (kt < 15) writeA((kt + 1) & 1, (kt & 1) ? laA : laB);  // data loaded 1 iter ago, already drained
  }

  #pragma unroll
  for (int m = 0; m < 4; ++m) {
    #pragma unroll
    for (int n = 0; n < 4; ++n) {
      int gm0 = m0 + wr * 64 + m * 16 + (ln >> 4) * 4;
      int gn = n0 + wc * 64 + n * 16 + (ln & 15);
      float bvv = bias[gn] * bscale;
      int hh = gn >> 6, d = gn & 63;
      if (z < 2) {
        unsigned short* o = z == 0 ? Qh : Kh;
        #pragma unroll
        for (int i = 0; i < 4; ++i) {
          int gm = gm0 + i;
          int bb = gm >> 10, t = gm & 1023;
          o[(size_t)((bb * 8 + hh) * 1024 + t) * 64 + d] = f2bf(acc[m][n][i] + bvv);
        }
        if (z == 1) {
          int bb = gm0 >> 10, t = gm0 & 1023;
          ushort4 pk;
          pk.x = f2bf(acc[m][n][0] + bvv);
          pk.y = f2bf(acc[m][n][1] + bvv);
          pk.z = f2bf(acc[m][n][2] + bvv);
          pk.w = f2bf(acc[m][n][3] + bvv);
          *(ushort4*)(Ktr + (size_t)((bb * 8 + hh) * 64 + d) * 1024 + t) = pk;
        }
      } else {
        int bb = gm0 >> 10, t = gm0 & 1023;
        int k5 = t & 31;
        int pos = (t & ~31) + ((k5 >> 2) & 3) * 8 + ((k5 >> 4) & 1) * 4;
        ushort4 pk;
        pk.x = f2bf(acc[m][n][0] + bvv);
        pk.y = f2bf(acc[m][n][1] + bvv);
        pk.z = f2bf(acc[m][n][2] + bvv);
        pk.w = f2bf(acc[m][n][3] + bvv);
        *(ushort4*)(Vt + (size_t)((bb * 8 + hh) * 64 + d) * 1024 + pos) = pk;
      }
    }
  }
}

// ---------------- final GEMM (XCD-panel-swizzled grid) ----------------
__global__ __launch_bounds__(256) void gemm_out_kernel(
    const unsigned short* __restrict__ A,
    const unsigned short* __restrict__ Bt,
    const float* __restrict__ bias,
    float* __restrict__ out) {
  __shared__ unsigned short Al[2][128 * 32];
  __shared__ unsigned short Bl[2][128 * 32];
  const int L = blockIdx.x;
  const int xcd = L & 7, sl = L >> 3;
  const int xb = sl & 3, yb = (sl >> 2) * 8 + xcd;
  const int tid = threadIdx.x, ln = tid & 63, wv = tid >> 6;
  const int m0 = yb * 128, n0 = xb * 128;
  const int wr = wv >> 1, wc = wv & 1;

  auto stage = [&](int kt, int buf) {
    int kb = kt * 32;
    #pragma unroll
    for (int u = 0; u < 2; ++u) {
      int n = tid + u * 256;
      int Lrow = n >> 2, kcs = n & 3;
      int kc = kcs ^ (Lrow & 3);
      GL16(A + (size_t)(m0 + Lrow) * 512 + kb + kc * 8, &Al[buf][n * 8]);
      GL16(Bt + (size_t)(n0 + Lrow) * 512 + kb + kc * 8, &Bl[buf][n * 8]);
    }
  };

  f32x4 acc[4][4] = {};
  stage(0, 0);
  for (int kt = 0; kt < 16; ++kt) {
    __syncthreads();
    if (kt < 15) stage(kt + 1, (kt + 1) & 1);
    const unsigned short* a_ = Al[kt & 1];
    const unsigned short* b_ = Bl[kt & 1];
    const int kc = ln >> 4;
    bf16x8 afr[4], bfr[4];
    #pragma unroll
    for (int m = 0; m < 4; ++m) {
      int r = wr * 64 + m * 16 + (ln & 15);
      afr[m] = *(const bf16x8*)(a_ + r * 32 + ((kc ^ (r & 3)) * 8));
    }
    #pragma unroll
    for (int n = 0; n < 4; ++n) {
      int r = wc * 64 + n * 16 + (ln & 15);
      bfr[n] = *(const bf16x8*)(b_ + r * 32 + ((kc ^ (r & 3)) * 8));
    }
    #pragma unroll
    for (int m = 0; m < 4; ++m)
      #pragma unroll
      for (int n = 0; n < 4; ++n)
        acc[m][n] = __builtin_amdgcn_mfma_f32_16x16x32_bf16(afr[m], bfr[n], acc[m][n], 0, 0, 0);
  }
  #pragma unroll
  for (int m = 0; m < 4; ++m)
    #pragma unroll
    for (int n = 0; n < 4; ++n) {
      int gm0 = m0 + wr * 64 + m * 16 + (ln >> 4) * 4;
      int gn = n0 + wc * 64 + n * 16 + (ln & 15);
      float bvv = bias[gn];
      #pragma unroll
      for (int i = 0; i < 4; ++i)
        out[(size_t)(gm0 + i) * 512 + gn] = acc[m][n][i] + bvv;
    }
}

// ---------------- Gram: M = K^T K split bf16 hi/lo + Ksum per (b,h) ----------------
__global__ __launch_bounds__(256, 1) void gram_kernel(
    const unsigned short* __restrict__ Ktr,
    unsigned short* __restrict__ Mhi, unsigned short* __restrict__ Mlo,
    float* __restrict__ KsumG) {
  __shared__ float KsR[4][64];
  const int bh = blockIdx.x;
  const unsigned short* Kb = Ktr + (size_t)bh * 65536;
  const int tid = threadIdx.x, ln = tid & 63, w = tid >> 6;
  const int c = ln & 15, g = ln >> 4;

  f32x4 acc[4] = {};
  #pragma unroll 2
  for (int kk = 0; kk < 32; ++kk) {
    bf16x8 af = *(const bf16x8*)(Kb + (size_t)(w * 16 + c) * 1024 + kk * 32 + g * 8);
    #pragma unroll
    for (int jt = 0; jt < 4; ++jt) {
      bf16x8 bf = *(const bf16x8*)(Kb + (size_t)(jt * 16 + c) * 1024 + kk * 32 + g * 8);
      acc[jt] = __builtin_amdgcn_mfma_f32_16x16x32_bf16(af, bf, acc[jt], 0, 0, 0);
    }
  }
  #pragma unroll
  for (int jt = 0; jt < 4; ++jt)
    #pragma unroll
    for (int r = 0; r < 4; ++r) {
      float v = acc[jt][r];
      unsigned short hi = f2bf(v);
      unsigned short lo = f2bf(v - bf2f(hi));
      size_t idx = (size_t)bh * 4096 + (w * 16 + g * 4 + r) * 64 + jt * 16 + c;
      Mhi[idx] = hi;
      Mlo[idx] = lo;
    }

  int d = tid & 63, seg = tid >> 6;
  float s = 0.f;
  for (int u = 0; u < 32; ++u) {
    bf16x8 v8 = *(const bf16x8*)(Kb + (size_t)d * 1024 + seg * 256 + u * 8);
    #pragma unroll
    for (int e = 0; e < 8; ++e) s += bf2f((unsigned short)v8[e]);
  }
  KsR[seg][d] = s;
  __syncthreads();
  if (tid < 64)
    KsumG[bh * 64 + tid] = KsR[0][tid] + KsR[1][tid] + KsR[2][tid] + KsR[3][tid];
}

// ---------------- coef via MFMA ----------------
__global__ __launch_bounds__(256) void coef_kernel(
    const unsigned short* __restrict__ Qh,
    const unsigned short* __restrict__ Mhi, const unsigned short* __restrict__ Mlo,
    const float* __restrict__ KsumG,
    const float* __restrict__ frac, const float* __restrict__ fstats,
    const float* __restrict__ alpha_pos, const float* __restrict__ alpha_neg,
    const float* __restrict__ gamma_p, const float* __restrict__ delta_p,
    const int* __restrict__ afb_p,
    float4* __restrict__ rowcG, float* __restrict__ rowShG) {
  const int bh = blockIdx.y;
  const int b = bh >> 3, h = bh & 7;
  const int tid = threadIdx.x, ln = tid & 63, w = tid >> 6;
  const int c = ln & 15, g = ln >> 4;
  const int qrow0 = blockIdx.x * 64 + w * 16;

  const unsigned short* qa = Qh + (size_t)(bh * 1024 + qrow0 + c) * 64 + g * 8;
  bf16x8 aQ0 = *(const bf16x8*)(qa);
  bf16x8 aQ1 = *(const bf16x8*)(qa + 32);

  const unsigned short* Mh = Mhi + (size_t)bh * 4096;
  const unsigned short* Ml = Mlo + (size_t)bh * 4096;
  f32x4 acc[4] = {};
  #pragma unroll
  for (int jt = 0; jt < 4; ++jt) {
    const unsigned short* mrow = Mh + (jt * 16 + c) * 64 + g * 8;
    const unsigned short* lrow = Ml + (jt * 16 + c) * 64 + g * 8;
    bf16x8 bh0 = *(const bf16x8*)(mrow);
    bf16x8 bh1 = *(const bf16x8*)(mrow + 32);
    bf16x8 bl0 = *(const bf16x8*)(lrow);
    bf16x8 bl1 = *(const bf16x8*)(lrow + 32);
    acc[jt] = __builtin_amdgcn_mfma_f32_16x16x32_bf16(aQ0, bh0, acc[jt], 0, 0, 0);
    acc[jt] = __builtin_amdgcn_mfma_f32_16x16x32_bf16(aQ1, bh1, acc[jt], 0, 0, 0);
    acc[jt] = __builtin_amdgcn_mfma_f32_16x16x32_bf16(aQ0, bl0, acc[jt], 0, 0, 0);
    acc[jt] = __builtin_amdgcn_mfma_f32_16x16x32_bf16(aQ1, bl1, acc[jt], 0, 0, 0);
  }

  float ks[4];
  #pragma unroll
  for (int jt = 0; jt < 4; ++jt) ks[jt] = KsumG[bh * 64 + jt * 16 + c];
  float pl[4], p2[4];
  #pragma unroll
  for (int r = 0; r < 4; ++r) {
    const unsigned short* qd = Qh + (size_t)(bh * 1024 + qrow0 + g * 4 + r) * 64 + c;
    float l = 0.f, s2 = 0.f;
    #pragma unroll
    for (int jt = 0; jt < 4; ++jt) {
      float qv = bf2f(qd[jt * 16]);
      s2 += qv * acc[jt][r];
      l += qv * ks[jt];
    }
    pl[r] = l; p2[r] = s2;
  }
  #pragma unroll
  for (int m = 1; m < 16; m <<= 1)
    #pragma unroll
    for (int r = 0; r < 4; ++r) {
      pl[r] += __shfl_xor(pl[r], m);
      p2[r] += __shfl_xor(p2[r], m);
    }

  if (c == 0) {
    const float gmv = *gamma_p, dlv = *delta_p;
    const float ap = alpha_pos[h], an = alpha_neg[h];
    const int afb = *afb_p;
    const float L2E = 1.4426950408889634f;
    #pragma unroll
    for (int r = 0; r < 4; ++r) {
      int q = qrow0 + g * 4 + r;
      float sl = pl[r], sl2 = p2[r];
      float mul_ = sl * (1.f / 1024.f);
      float varl = fmaxf((sl2 - 1024.f * mul_ * mul_) * (1.f / 1023.f), 0.f);
      float cA = gmv / (sqrtf(varl) + EPS);
      float4 st = *(const float4*)(fstats + (size_t)(b * 1024 + q) * 4);
      float msum = ap * st.x + an * st.y;
      float msq = ap * ap * st.z + an * an * st.w;
      float mus = msum * (1.f / 1024.f);
      float vars = fmaxf((msq - 1024.f * mus * mus) * (1.f / 1023.f), 0.f);
      float cB = afb ? (dlv / (sqrtf(vars) + EPS)) : 0.f;
      float4 rc;
      rc.x = frac[b * 1024 + q];
      rc.y = cA * L2E;
      rc.z = cB * ap * L2E;
      rc.w = cB * an * L2E;
      rowcG[(size_t)bh * 1024 + q] = rc;
      rowShG[(size_t)bh * 1024 + q] = (cA * mul_ + cB * mus) * L2E;
    }
  }
}

// ---------------- flash (round-12/14 proven): (bh,128q)/block, 4 waves x 32q ----------------
__global__ __launch_bounds__(256, 2) void flash_kernel(
    const unsigned short* __restrict__ Qh,
    const unsigned short* __restrict__ Kh,
    const unsigned short* __restrict__ Vt,
    unsigned short* __restrict__ attnO,
    const float* __restrict__ frac,
    const float4* __restrict__ rowcG, const float* __restrict__ rowShG) {
  extern __shared__ char smem[];
  unsigned short* Kl = (unsigned short*)smem;
  unsigned short* Vl = (unsigned short*)(smem + 32768);
  float* fk = (float*)(smem + 65536);
  float4* rowcS = (float4*)(smem + 69632);
  float* rowShS = (float*)(smem + 71680);
  float* psumW = (float*)(smem + 72192);

  const int L = blockIdx.x;
  const int xcd = L & 7, s = L >> 3;
  const int bh = xcd + 8 * (s >> 3);
  const int t0 = (s & 7) * 128;
  const int b = bh >> 3, h = bh & 7;
  const int tid = threadIdx.x, ln = tid & 63, w = tid >> 6;
  const int c = ln & 15, g = ln >> 4;

  auto stageK = [&](int t, int buf) {
    #pragma unroll
    for (int u = 0; u < 4; ++u) {
      int n = tid + u * 256;
      int row = n >> 3, kc = (n & 7) ^ (row & 7);
      GL16(Kh + (size_t)(bh * 1024 + t * 128 + row) * 64 + kc * 8,
           Kl + buf * 8192 + n * 8);
    }
  };
  auto stageV = [&](int t, int buf) {
    #pragma unroll
    for (int u = 0; u < 4; ++u) {
      int n = tid + u * 256;
      int d = n >> 4, ch = n & 15;
      GL16(Vt + (size_t)(bh * 64 + d) * 1024 + t * 128 + (ch ^ (d & 15)) * 8,
           Vl + buf * 8192 + n * 8);
    }
  };

  stageK(0, 0);
  stageV(0, 0);
  GL16(frac + b * 1024 + tid * 4, fk + tid * 4);
  if (tid < 128) GL16(rowcG + (size_t)bh * 1024 + t0 + tid, rowcS + tid);
  if (tid < 32) GL16(rowShG + (size_t)bh * 1024 + t0 + tid * 4, rowShS + tid * 4);

  bf16x8 qf[2][2];
  #pragma unroll
  for (int qh = 0; qh < 2; ++qh) {
    const unsigned short* qrow =
        Qh + (size_t)(bh * 1024 + t0 + w * 32 + qh * 16 + c) * 64 + g * 8;
    qf[qh][0] = *(const bf16x8*)(qrow);
    qf[qh][1] = *(const bf16x8*)(qrow + 32);
  }
  __syncthreads();

  const float4 rc0 = rowcS[w * 32 + c], rc1 = rowcS[w * 32 + 16 + c];
  const float sh0 = rowShS[w * 32 + c], sh1 = rowShS[w * 32 + 16 + c];

  f32x4 acc[2][4] = {};
  float ps0a = 0.f, ps0b = 0.f, ps1a = 0.f, ps1b = 0.f;

  for (int t = 0; t < 8; ++t) {
    if (t) __syncthreads();
    if (t < 7) { stageK(t + 1, (t + 1) & 1); stageV(t + 1, (t + 1) & 1); }
    const unsigned short* kb_ = Kl + (t & 1) * 8192;
    const unsigned short* vb_ = Vl + (t & 1) * 8192;

    f32x4 S[8][2];
    #pragma unroll
    for (int kg = 0; kg < 8; ++kg) {
      int krow = kg * 16 + c;
      bf16x8 kf0 = *(const bf16x8*)(kb_ + krow * 64 + ((g ^ (krow & 7)) * 8));
      bf16x8 kf1 = *(const bf16x8*)(kb_ + krow * 64 + (((g + 4) ^ (krow & 7)) * 8));
      #pragma unroll
      for (int qh = 0; qh < 2; ++qh) {
        f32x4 a = {0.f, 0.f, 0.f, 0.f};
        a = __builtin_amdgcn_mfma_f32_16x16x32_bf16(kf0, qf[qh][0], a, 0, 0, 0);
        a = __builtin_amdgcn_mfma_f32_16x16x32_bf16(kf1, qf[qh][1], a, 0, 0, 0);
        S[kg][qh] = a;
      }
    }

    #pragma unroll
    for (int kg = 0; kg < 8; ++kg) {
      float4 f4 = *(const float4*)(&fk[t * 128 + kg * 16 + g * 4]);
      #pragma unroll
      for (int r = 0; r < 4; ++r) {
        float f = (r == 0) ? f4.x : (r == 1) ? f4.y : (r == 2) ? f4.z : f4.w;
        {
          float dd = f - rc0.x, x = f * rc0.x * dd;
          float sel = (dd >= 0.f) ? rc0.z : rc0.w;
          float e = __builtin_amdgcn_exp2f(fmaf(rc0.y, S[kg][0][r], fmaf(x, sel, -sh0)));
          if (kg & 1) ps0a += e; else ps0b += e;
          S[kg][0][r] = e;
        }
        {
          float dd = f - rc1.x, x = f * rc1.x * dd;
          float sel = (dd >= 0.f) ? rc1.z : rc1.w;
          float e = __builtin_amdgcn_exp2f(fmaf(rc1.y, S[kg][1][r], fmaf(x, sel, -sh1)));
          if (kg & 1) ps1a += e; else ps1b += e;
          S[kg][1][r] = e;
        }
      }
    }

    __builtin_amdgcn_s_setprio(1);
    #pragma unroll
    for (int ks = 0; ks < 4; ++ks) {
      union AW { unsigned u[4]; bf16x8 v; } aw0, aw1;
      #pragma unroll
      for (int m = 0; m < 4; ++m) {
        int kg2 = 2 * ks + (m >> 1), rr = (m & 1) * 2;
        unsigned a0 = __float_as_uint(S[kg2][0][rr]), a1 = __float_as_uint(S[kg2][0][rr + 1]);
        aw0.u[m] = ((a1 + 0x8000u) & 0xFFFF0000u) | ((a0 + 0x8000u) >> 16);
        unsigned b0 = __float_as_uint(S[kg2][1][rr]), b1 = __float_as_uint(S[kg2][1][rr + 1]);
        aw1.u[m] = ((b1 + 0x8000u) & 0xFFFF0000u) | ((b0 + 0x8000u) >> 16);
      }
      #pragma unroll
      for (int db = 0; db < 4; ++db) {
        int d = db * 16 + c;
        bf16x8 bv = *(const bf16x8*)(vb_ + d * 128 + (((ks * 4 + g) ^ c) * 8));
        acc[0][db] = __builtin_amdgcn_mfma_f32_16x16x32_bf16(aw0.v, bv, acc[0][db], 0, 0, 0);
        acc[1][db] = __builtin_amdgcn_mfma_f32_16x16x32_bf16(aw1.v, bv, acc[1][db], 0, 0, 0);
      }
    }
    __builtin_amdgcn_s_setprio(0);
  }

  float ps0 = ps0a + ps0b, ps1 = ps1a + ps1b;
  ps0 += __shfl_xor(ps0, 16); ps0 += __shfl_xor(ps0, 32);
  ps1 += __shfl_xor(ps1, 16); ps1 += __shfl_xor(ps1, 32);
  if (g == 0) { psumW[w * 32 + c] = ps0; psumW[w * 32 + 16 + c] = ps1; }

  #pragma unroll
  for (int qh = 0; qh < 2; ++qh)
    #pragma unroll
    for (int r = 0; r < 4; ++r) {
      float rcp = 1.f / psumW[w * 32 + qh * 16 + g * 4 + r];
      int qg = t0 + w * 32 + qh * 16 + g * 4 + r;
      unsigned short* orow = attnO + (size_t)(b * 1024 + qg) * 512 + h * 64 + c;
      #pragma unroll
      for (int db = 0; db < 4; ++db)
        orow[db * 16] = f2bf(acc[qh][db][r] * rcp);
    }
}

extern "C" void kernel_launch(void* const* d_in, const int* in_sizes, int n_in,
                              void* d_out, int out_size, void* d_ws, size_t ws_size,
                              hipStream_t stream) {
  const float* q = (const float*)d_in[0];
  const float* k = (const float*)d_in[1];
  const float* v = (const float*)d_in[2];
  const float* frac = (const float*)d_in[3];
  const float* Wq = (const float*)d_in[4];
  const float* bq = (const float*)d_in[5];
  const float* Wk = (const float*)d_in[6];
  const float* bk = (const float*)d_in[7];
  const float* Wv = (const float*)d_in[8];
  const float* bv = (const float*)d_in[9];
  const float* Wo = (const float*)d_in[10];
  const float* bo = (const float*)d_in[11];
  const float* ap = (const float*)d_in[12];
  const float* an = (const float*)d_in[13];
  const float* gm = (const float*)d_in[14];
  const float* dl = (const float*)d_in[15];
  const int* afb = (const int*)d_in[16];

  char* ws = (char*)d_ws;
  unsigned short* wqT = (unsigned short*)(ws + 0);
  unsigned short* wkT = (unsigned short*)(ws + 524288);
  unsigned short* wvT = (unsigned short*)(ws + 1048576);
  unsigned short* woT = (unsigned short*)(ws + 1572864);
  unsigned short* Qh = (unsigned short*)(ws + 2097152);
  unsigned short* Kh = (unsigned short*)(ws + 10485760);
  unsigned short* Ktr = (unsigned short*)(ws + 18874368);
  unsigned short* Vt = (unsigned short*)(ws + 27262976);
  unsigned short* aO = (unsigned short*)(ws + 35651584);
  float* fst = (float*)(ws + 44040192);
  unsigned short* Mhi = (unsigned short*)(ws + 44171264);
  unsigned short* Mlo = (unsigned short*)(ws + 44695552);
  float* KsumG = (float*)(ws + 45219840);
  float4* rowcG = (float4*)(ws + 45236224);
  float* rowShG = (float*)(ws + 46284800);

  hipFuncSetAttribute((const void*)flash_kernel,
                      hipFuncAttributeMaxDynamicSharedMemorySize, FLASH_SMEM);

  prep_kernel<<<3072, 256, 0, stream>>>(Wq, Wk, Wv, Wo, wqT, wkT, wvT, woT, frac, fst);
  qkv_gemm_kernel<<<768, 256, 0, stream>>>(q, k, v, wqT, wkT, wvT,
                                           bq, bk, bv, Qh, Kh, Ktr, Vt);
  gram_kernel<<<64, 256, 0, stream>>>(Ktr, Mhi, Mlo, KsumG);
  coef_kernel<<<dim3(16, 64), 256, 0, stream>>>(Qh, Mhi, Mlo, KsumG, frac, fst,
                                                ap, an, gm, dl, afb, rowcG, rowShG);
  flash_kernel<<<512, 256, FLASH_SMEM, stream>>>(Qh, Kh, Vt, aO, frac, rowcG, rowShG);
  gemm_out_kernel<<<256, 256, 0, stream>>>(aO, woT, bo, (float*)d_out);
}

// Round 17
// 125.288 us; speedup vs baseline: 1.4972x; 1.4972x over previous
//
#include <hip/hip_runtime.h>
#include <hip/hip_bf16.h>

#define EPS 1e-5f
#define FLASH_SMEM 72704

typedef short bf16x8 __attribute__((ext_vector_type(8)));
typedef float f32x4 __attribute__((ext_vector_type(4)));

#define GL16(gp, lp) __builtin_amdgcn_global_load_lds( \
    (const __attribute__((address_space(1))) void*)(gp), \
    (__attribute__((address_space(3))) void*)(lp), 16, 0, 0)

__device__ __forceinline__ unsigned short f2bf(float f) {
  union { float f; unsigned u; } v; v.f = f;
  return (unsigned short)((v.u + 0x7FFFu + ((v.u >> 16) & 1u)) >> 16);
}
__device__ __forceinline__ float bf2f(unsigned short u) {
  return __uint_as_float(((unsigned)u) << 16);
}

// ---------------- merged prep: 4 weight transposes + frac stats in one launch ----------------
__global__ void prep_kernel(const float* __restrict__ W0, const float* __restrict__ W1,
                            const float* __restrict__ W2, const float* __restrict__ W3,
                            unsigned short* __restrict__ T0, unsigned short* __restrict__ T1,
                            unsigned short* __restrict__ T2, unsigned short* __restrict__ T3,
                            const float* __restrict__ frac, float* __restrict__ fstats) {
  __shared__ float tile[32][33];
  const int L = blockIdx.x;
  if (L < 1024) {
    int z = L >> 8, rem = L & 255;
    const float* W = z == 0 ? W0 : z == 1 ? W1 : z == 2 ? W2 : W3;
    unsigned short* Wt = z == 0 ? T0 : z == 1 ? T1 : z == 2 ? T2 : T3;
    float scale = (z == 0) ? 0.125f : 1.0f;
    int n0 = (rem & 15) * 32, k0 = (rem >> 4) * 32;
    int c = threadIdx.x & 31, r0 = threadIdx.x >> 5;
    #pragma unroll
    for (int rr = 0; rr < 32; rr += 8)
      tile[r0 + rr][c] = W[(k0 + r0 + rr) * 512 + n0 + c];
    __syncthreads();
    #pragma unroll
    for (int rr = 0; rr < 32; rr += 8)
      Wt[(n0 + r0 + rr) * 512 + k0 + c] = f2bf(tile[c][r0 + rr] * scale);
  } else {
    int wid = (int)(((L - 1024) * 256 + threadIdx.x) >> 6);
    int ln = threadIdx.x & 63;
    int b = wid >> 10, q = wid & 1023;
    const float* fr = frac + b * 1024;
    float fq = fr[q];
    float sp = 0.f, sn = 0.f, sp2 = 0.f, sn2 = 0.f;
    for (int i = ln; i < 1024; i += 64) {
      float f = fr[i];
      float dm = (f - fq) * (fq * f);
      float p = fmaxf(dm, 0.f), nn = fminf(dm, 0.f);
      sp += p; sn += nn; sp2 += p * p; sn2 += nn * nn;
    }
    #pragma unroll
    for (int m = 32; m; m >>= 1) {
      sp += __shfl_xor(sp, m); sn += __shfl_xor(sn, m);
      sp2 += __shfl_xor(sp2, m); sn2 += __shfl_xor(sn2, m);
    }
    if (ln == 0) {
      float4 o; o.x = sp; o.y = sn; o.z = sp2; o.w = sn2;
      *(float4*)(fstats + (size_t)wid * 4) = o;
    }
  }
}

// ---------------- fused QKV GEMM (round-14 proven): 128-row tiles, panel swizzle, distance-1 ----------------
__global__ __launch_bounds__(256) void qkv_gemm_kernel(
    const float* __restrict__ Aq, const float* __restrict__ Ak, const float* __restrict__ Av,
    const unsigned short* __restrict__ WqT, const unsigned short* __restrict__ WkT,
    const unsigned short* __restrict__ WvT,
    const float* __restrict__ bq, const float* __restrict__ bk, const float* __restrict__ bv,
    unsigned short* __restrict__ Qh, unsigned short* __restrict__ Kh,
    unsigned short* __restrict__ Ktr, unsigned short* __restrict__ Vt) {
  __shared__ unsigned short Al[2][128 * 32];
  __shared__ unsigned short Bl[2][128 * 32];
  const int L = blockIdx.x;
  const int xcd = L & 7, sl = L >> 3;
  const int xb = sl & 3;
  const int P = (sl >> 2) * 8 + xcd;   // panel id 0..191
  const int yb = P & 63, z = P >> 6;

  const float* A = z == 0 ? Aq : z == 1 ? Ak : Av;
  const unsigned short* Bt = z == 0 ? WqT : z == 1 ? WkT : WvT;
  const float* bias = z == 0 ? bq : z == 1 ? bk : bv;
  const float bscale = (z == 0) ? 0.125f : 1.0f;

  const int tid = threadIdx.x, ln = tid & 63, wv = tid >> 6;
  const int m0 = yb * 128, n0 = xb * 128;
  const int wr = wv >> 1, wc = wv & 1;
  const int arow = tid >> 1;
  const int agh = (tid & 1) * 2;

  auto stageB = [&](int kt, int buf) {
    int kb = kt * 32;
    #pragma unroll
    for (int u = 0; u < 2; ++u) {
      int n = tid + u * 256;
      int Lrow = n >> 2, kcs = n & 3;
      int kc = kcs ^ (Lrow & 3);
      GL16(Bt + (size_t)(n0 + Lrow) * 512 + kb + kc * 8, &Bl[buf][n * 8]);
    }
  };
  auto loadA = [&](int kt, float4* la) {
    const float* src = A + (size_t)(m0 + arow) * 512 + kt * 32 + agh * 8;
    la[0] = *(const float4*)(src);
    la[1] = *(const float4*)(src + 4);
    la[2] = *(const float4*)(src + 8);
    la[3] = *(const float4*)(src + 12);
  };
  auto writeA = [&](int buf, const float4* la) {
    #pragma unroll
    for (int G = 0; G < 2; ++G) {
      union { bf16x8 v; unsigned short u[8]; } pk;
      float4 a = la[2 * G], b2 = la[2 * G + 1];
      pk.u[0] = f2bf(a.x); pk.u[1] = f2bf(a.y); pk.u[2] = f2bf(a.z); pk.u[3] = f2bf(a.w);
      pk.u[4] = f2bf(b2.x); pk.u[5] = f2bf(b2.y); pk.u[6] = f2bf(b2.z); pk.u[7] = f2bf(b2.w);
      int dg = (agh + G) ^ (arow & 3);
      *(bf16x8*)(&Al[buf][arow * 32 + dg * 8]) = pk.v;
    }
  };

  f32x4 acc[4][4] = {};
  float4 la[4];
  loadA(0, la); writeA(0, la);
  stageB(0, 0);
  for (int kt = 0; kt < 16; ++kt) {
    __syncthreads();
    if (kt < 15) { loadA(kt + 1, la); stageB(kt + 1, (kt + 1) & 1); }
    const unsigned short* a_ = Al[kt & 1];
    const unsigned short* b_ = Bl[kt & 1];
    const int kc = ln >> 4;
    bf16x8 afr[4], bfr[4];
    #pragma unroll
    for (int m = 0; m < 4; ++m) {
      int r = wr * 64 + m * 16 + (ln & 15);
      afr[m] = *(const bf16x8*)(a_ + r * 32 + ((kc ^ (r & 3)) * 8));
    }
    #pragma unroll
    for (int n = 0; n < 4; ++n) {
      int r = wc * 64 + n * 16 + (ln & 15);
      bfr[n] = *(const bf16x8*)(b_ + r * 32 + ((kc ^ (r & 3)) * 8));
    }
    #pragma unroll
    for (int m = 0; m < 4; ++m)
      #pragma unroll
      for (int n = 0; n < 4; ++n)
        acc[m][n] = __builtin_amdgcn_mfma_f32_16x16x32_bf16(afr[m], bfr[n], acc[m][n], 0, 0, 0);
    if (kt < 15) writeA((kt + 1) & 1, la);
  }

  #pragma unroll
  for (int m = 0; m < 4; ++m) {
    #pragma unroll
    for (int n = 0; n < 4; ++n) {
      int gm0 = m0 + wr * 64 + m * 16 + (ln >> 4) * 4;
      int gn = n0 + wc * 64 + n * 16 + (ln & 15);
      float bvv = bias[gn] * bscale;
      int hh = gn >> 6, d = gn & 63;
      if (z < 2) {
        unsigned short* o = z == 0 ? Qh : Kh;
        #pragma unroll
        for (int i = 0; i < 4; ++i) {
          int gm = gm0 + i;
          int bb = gm >> 10, t = gm & 1023;
          o[(size_t)((bb * 8 + hh) * 1024 + t) * 64 + d] = f2bf(acc[m][n][i] + bvv);
        }
        if (z == 1) {
          int bb = gm0 >> 10, t = gm0 & 1023;
          ushort4 pk;
          pk.x = f2bf(acc[m][n][0] + bvv);
          pk.y = f2bf(acc[m][n][1] + bvv);
          pk.z = f2bf(acc[m][n][2] + bvv);
          pk.w = f2bf(acc[m][n][3] + bvv);
          *(ushort4*)(Ktr + (size_t)((bb * 8 + hh) * 64 + d) * 1024 + t) = pk;
        }
      } else {
        int bb = gm0 >> 10, t = gm0 & 1023;
        int k5 = t & 31;
        int pos = (t & ~31) + ((k5 >> 2) & 3) * 8 + ((k5 >> 4) & 1) * 4;
        ushort4 pk;
        pk.x = f2bf(acc[m][n][0] + bvv);
        pk.y = f2bf(acc[m][n][1] + bvv);
        pk.z = f2bf(acc[m][n][2] + bvv);
        pk.w = f2bf(acc[m][n][3] + bvv);
        *(ushort4*)(Vt + (size_t)((bb * 8 + hh) * 64 + d) * 1024 + pos) = pk;
      }
    }
  }
}

// ---------------- final GEMM (XCD-panel-swizzled grid) ----------------
__global__ __launch_bounds__(256) void gemm_out_kernel(
    const unsigned short* __restrict__ A,
    const unsigned short* __restrict__ Bt,
    const float* __restrict__ bias,
    float* __restrict__ out) {
  __shared__ unsigned short Al[2][128 * 32];
  __shared__ unsigned short Bl[2][128 * 32];
  const int L = blockIdx.x;
  const int xcd = L & 7, sl = L >> 3;
  const int xb = sl & 3, yb = (sl >> 2) * 8 + xcd;
  const int tid = threadIdx.x, ln = tid & 63, wv = tid >> 6;
  const int m0 = yb * 128, n0 = xb * 128;
  const int wr = wv >> 1, wc = wv & 1;

  auto stage = [&](int kt, int buf) {
    int kb = kt * 32;
    #pragma unroll
    for (int u = 0; u < 2; ++u) {
      int n = tid + u * 256;
      int Lrow = n >> 2, kcs = n & 3;
      int kc = kcs ^ (Lrow & 3);
      GL16(A + (size_t)(m0 + Lrow) * 512 + kb + kc * 8, &Al[buf][n * 8]);
      GL16(Bt + (size_t)(n0 + Lrow) * 512 + kb + kc * 8, &Bl[buf][n * 8]);
    }
  };

  f32x4 acc[4][4] = {};
  stage(0, 0);
  for (int kt = 0; kt < 16; ++kt) {
    __syncthreads();
    if (kt < 15) stage(kt + 1, (kt + 1) & 1);
    const unsigned short* a_ = Al[kt & 1];
    const unsigned short* b_ = Bl[kt & 1];
    const int kc = ln >> 4;
    bf16x8 afr[4], bfr[4];
    #pragma unroll
    for (int m = 0; m < 4; ++m) {
      int r = wr * 64 + m * 16 + (ln & 15);
      afr[m] = *(const bf16x8*)(a_ + r * 32 + ((kc ^ (r & 3)) * 8));
    }
    #pragma unroll
    for (int n = 0; n < 4; ++n) {
      int r = wc * 64 + n * 16 + (ln & 15);
      bfr[n] = *(const bf16x8*)(b_ + r * 32 + ((kc ^ (r & 3)) * 8));
    }
    #pragma unroll
    for (int m = 0; m < 4; ++m)
      #pragma unroll
      for (int n = 0; n < 4; ++n)
        acc[m][n] = __builtin_amdgcn_mfma_f32_16x16x32_bf16(afr[m], bfr[n], acc[m][n], 0, 0, 0);
  }
  #pragma unroll
  for (int m = 0; m < 4; ++m)
    #pragma unroll
    for (int n = 0; n < 4; ++n) {
      int gm0 = m0 + wr * 64 + m * 16 + (ln >> 4) * 4;
      int gn = n0 + wc * 64 + n * 16 + (ln & 15);
      float bvv = bias[gn];
      #pragma unroll
      for (int i = 0; i < 4; ++i)
        out[(size_t)(gm0 + i) * 512 + gn] = acc[m][n][i] + bvv;
    }
}

// ---------------- Gram: M = K^T K split bf16 hi/lo + Ksum per (b,h) ----------------
__global__ __launch_bounds__(256, 1) void gram_kernel(
    const unsigned short* __restrict__ Ktr,
    unsigned short* __restrict__ Mhi, unsigned short* __restrict__ Mlo,
    float* __restrict__ KsumG) {
  __shared__ float KsR[4][64];
  const int bh = blockIdx.x;
  const unsigned short* Kb = Ktr + (size_t)bh * 65536;
  const int tid = threadIdx.x, ln = tid & 63, w = tid >> 6;
  const int c = ln & 15, g = ln >> 4;

  f32x4 acc[4] = {};
  #pragma unroll 2
  for (int kk = 0; kk < 32; ++kk) {
    bf16x8 af = *(const bf16x8*)(Kb + (size_t)(w * 16 + c) * 1024 + kk * 32 + g * 8);
    #pragma unroll
    for (int jt = 0; jt < 4; ++jt) {
      bf16x8 bf = *(const bf16x8*)(Kb + (size_t)(jt * 16 + c) * 1024 + kk * 32 + g * 8);
      acc[jt] = __builtin_amdgcn_mfma_f32_16x16x32_bf16(af, bf, acc[jt], 0, 0, 0);
    }
  }
  #pragma unroll
  for (int jt = 0; jt < 4; ++jt)
    #pragma unroll
    for (int r = 0; r < 4; ++r) {
      float v = acc[jt][r];
      unsigned short hi = f2bf(v);
      unsigned short lo = f2bf(v - bf2f(hi));
      size_t idx = (size_t)bh * 4096 + (w * 16 + g * 4 + r) * 64 + jt * 16 + c;
      Mhi[idx] = hi;
      Mlo[idx] = lo;
    }

  int d = tid & 63, seg = tid >> 6;
  float s = 0.f;
  for (int u = 0; u < 32; ++u) {
    bf16x8 v8 = *(const bf16x8*)(Kb + (size_t)d * 1024 + seg * 256 + u * 8);
    #pragma unroll
    for (int e = 0; e < 8; ++e) s += bf2f((unsigned short)v8[e]);
  }
  KsR[seg][d] = s;
  __syncthreads();
  if (tid < 64)
    KsumG[bh * 64 + tid] = KsR[0][tid] + KsR[1][tid] + KsR[2][tid] + KsR[3][tid];
}

// ---------------- coef via MFMA ----------------
__global__ __launch_bounds__(256) void coef_kernel(
    const unsigned short* __restrict__ Qh,
    const unsigned short* __restrict__ Mhi, const unsigned short* __restrict__ Mlo,
    const float* __restrict__ KsumG,
    const float* __restrict__ frac, const float* __restrict__ fstats,
    const float* __restrict__ alpha_pos, const float* __restrict__ alpha_neg,
    const float* __restrict__ gamma_p, const float* __restrict__ delta_p,
    const int* __restrict__ afb_p,
    float4* __restrict__ rowcG, float* __restrict__ rowShG) {
  const int bh = blockIdx.y;
  const int b = bh >> 3, h = bh & 7;
  const int tid = threadIdx.x, ln = tid & 63, w = tid >> 6;
  const int c = ln & 15, g = ln >> 4;
  const int qrow0 = blockIdx.x * 64 + w * 16;

  const unsigned short* qa = Qh + (size_t)(bh * 1024 + qrow0 + c) * 64 + g * 8;
  bf16x8 aQ0 = *(const bf16x8*)(qa);
  bf16x8 aQ1 = *(const bf16x8*)(qa + 32);

  const unsigned short* Mh = Mhi + (size_t)bh * 4096;
  const unsigned short* Ml = Mlo + (size_t)bh * 4096;
  f32x4 acc[4] = {};
  #pragma unroll
  for (int jt = 0; jt < 4; ++jt) {
    const unsigned short* mrow = Mh + (jt * 16 + c) * 64 + g * 8;
    const unsigned short* lrow = Ml + (jt * 16 + c) * 64 + g * 8;
    bf16x8 bh0 = *(const bf16x8*)(mrow);
    bf16x8 bh1 = *(const bf16x8*)(mrow + 32);
    bf16x8 bl0 = *(const bf16x8*)(lrow);
    bf16x8 bl1 = *(const bf16x8*)(lrow + 32);
    acc[jt] = __builtin_amdgcn_mfma_f32_16x16x32_bf16(aQ0, bh0, acc[jt], 0, 0, 0);
    acc[jt] = __builtin_amdgcn_mfma_f32_16x16x32_bf16(aQ1, bh1, acc[jt], 0, 0, 0);
    acc[jt] = __builtin_amdgcn_mfma_f32_16x16x32_bf16(aQ0, bl0, acc[jt], 0, 0, 0);
    acc[jt] = __builtin_amdgcn_mfma_f32_16x16x32_bf16(aQ1, bl1, acc[jt], 0, 0, 0);
  }

  float ks[4];
  #pragma unroll
  for (int jt = 0; jt < 4; ++jt) ks[jt] = KsumG[bh * 64 + jt * 16 + c];
  float pl[4], p2[4];
  #pragma unroll
  for (int r = 0; r < 4; ++r) {
    const unsigned short* qd = Qh + (size_t)(bh * 1024 + qrow0 + g * 4 + r) * 64 + c;
    float l = 0.f, s2 = 0.f;
    #pragma unroll
    for (int jt = 0; jt < 4; ++jt) {
      float qv = bf2f(qd[jt * 16]);
      s2 += qv * acc[jt][r];
      l += qv * ks[jt];
    }
    pl[r] = l; p2[r] = s2;
  }
  #pragma unroll
  for (int m = 1; m < 16; m <<= 1)
    #pragma unroll
    for (int r = 0; r < 4; ++r) {
      pl[r] += __shfl_xor(pl[r], m);
      p2[r] += __shfl_xor(p2[r], m);
    }

  if (c == 0) {
    const float gmv = *gamma_p, dlv = *delta_p;
    const float ap = alpha_pos[h], an = alpha_neg[h];
    const int afb = *afb_p;
    const float L2E = 1.4426950408889634f;
    #pragma unroll
    for (int r = 0; r < 4; ++r) {
      int q = qrow0 + g * 4 + r;
      float sl = pl[r], sl2 = p2[r];
      float mul_ = sl * (1.f / 1024.f);
      float varl = fmaxf((sl2 - 1024.f * mul_ * mul_) * (1.f / 1023.f), 0.f);
      float cA = gmv / (sqrtf(varl) + EPS);
      float4 st = *(const float4*)(fstats + (size_t)(b * 1024 + q) * 4);
      float msum = ap * st.x + an * st.y;
      float msq = ap * ap * st.z + an * an * st.w;
      float mus = msum * (1.f / 1024.f);
      float vars = fmaxf((msq - 1024.f * mus * mus) * (1.f / 1023.f), 0.f);
      float cB = afb ? (dlv / (sqrtf(vars) + EPS)) : 0.f;
      float4 rc;
      rc.x = frac[b * 1024 + q];
      rc.y = cA * L2E;
      rc.z = cB * ap * L2E;
      rc.w = cB * an * L2E;
      rowcG[(size_t)bh * 1024 + q] = rc;
      rowShG[(size_t)bh * 1024 + q] = (cA * mul_ + cB * mus) * L2E;
    }
  }
}

// ---------------- flash (round-12/14 proven): (bh,128q)/block, 4 waves x 32q ----------------
__global__ __launch_bounds__(256, 2) void flash_kernel(
    const unsigned short* __restrict__ Qh,
    const unsigned short* __restrict__ Kh,
    const unsigned short* __restrict__ Vt,
    unsigned short* __restrict__ attnO,
    const float* __restrict__ frac,
    const float4* __restrict__ rowcG, const float* __restrict__ rowShG) {
  extern __shared__ char smem[];
  unsigned short* Kl = (unsigned short*)smem;
  unsigned short* Vl = (unsigned short*)(smem + 32768);
  float* fk = (float*)(smem + 65536);
  float4* rowcS = (float4*)(smem + 69632);
  float* rowShS = (float*)(smem + 71680);
  float* psumW = (float*)(smem + 72192);

  const int L = blockIdx.x;
  const int xcd = L & 7, s = L >> 3;
  const int bh = xcd + 8 * (s >> 3);
  const int t0 = (s & 7) * 128;
  const int b = bh >> 3, h = bh & 7;
  const int tid = threadIdx.x, ln = tid & 63, w = tid >> 6;
  const int c = ln & 15, g = ln >> 4;

  auto stageK = [&](int t, int buf) {
    #pragma unroll
    for (int u = 0; u < 4; ++u) {
      int n = tid + u * 256;
      int row = n >> 3, kc = (n & 7) ^ (row & 7);
      GL16(Kh + (size_t)(bh * 1024 + t * 128 + row) * 64 + kc * 8,
           Kl + buf * 8192 + n * 8);
    }
  };
  auto stageV = [&](int t, int buf) {
    #pragma unroll
    for (int u = 0; u < 4; ++u) {
      int n = tid + u * 256;
      int d = n >> 4, ch = n & 15;
      GL16(Vt + (size_t)(bh * 64 + d) * 1024 + t * 128 + (ch ^ (d & 15)) * 8,
           Vl + buf * 8192 + n * 8);
    }
  };

  stageK(0, 0);
  stageV(0, 0);
  GL16(frac + b * 1024 + tid * 4, fk + tid * 4);
  if (tid < 128) GL16(rowcG + (size_t)bh * 1024 + t0 + tid, rowcS + tid);
  if (tid < 32) GL16(rowShG + (size_t)bh * 1024 + t0 + tid * 4, rowShS + tid * 4);

  bf16x8 qf[2][2];
  #pragma unroll
  for (int qh = 0; qh < 2; ++qh) {
    const unsigned short* qrow =
        Qh + (size_t)(bh * 1024 + t0 + w * 32 + qh * 16 + c) * 64 + g * 8;
    qf[qh][0] = *(const bf16x8*)(qrow);
    qf[qh][1] = *(const bf16x8*)(qrow + 32);
  }
  __syncthreads();

  const float4 rc0 = rowcS[w * 32 + c], rc1 = rowcS[w * 32 + 16 + c];
  const float sh0 = rowShS[w * 32 + c], sh1 = rowShS[w * 32 + 16 + c];

  f32x4 acc[2][4] = {};
  float ps0a = 0.f, ps0b = 0.f, ps1a = 0.f, ps1b = 0.f;

  for (int t = 0; t < 8; ++t) {
    if (t) __syncthreads();
    if (t < 7) { stageK(t + 1, (t + 1) & 1); stageV(t + 1, (t + 1) & 1); }
    const unsigned short* kb_ = Kl + (t & 1) * 8192;
    const unsigned short* vb_ = Vl + (t & 1) * 8192;

    f32x4 S[8][2];
    #pragma unroll
    for (int kg = 0; kg < 8; ++kg) {
      int krow = kg * 16 + c;
      bf16x8 kf0 = *(const bf16x8*)(kb_ + krow * 64 + ((g ^ (krow & 7)) * 8));
      bf16x8 kf1 = *(const bf16x8*)(kb_ + krow * 64 + (((g + 4) ^ (krow & 7)) * 8));
      #pragma unroll
      for (int qh = 0; qh < 2; ++qh) {
        f32x4 a = {0.f, 0.f, 0.f, 0.f};
        a = __builtin_amdgcn_mfma_f32_16x16x32_bf16(kf0, qf[qh][0], a, 0, 0, 0);
        a = __builtin_amdgcn_mfma_f32_16x16x32_bf16(kf1, qf[qh][1], a, 0, 0, 0);
        S[kg][qh] = a;
      }
    }

    #pragma unroll
    for (int kg = 0; kg < 8; ++kg) {
      float4 f4 = *(const float4*)(&fk[t * 128 + kg * 16 + g * 4]);
      #pragma unroll
      for (int r = 0; r < 4; ++r) {
        float f = (r == 0) ? f4.x : (r == 1) ? f4.y : (r == 2) ? f4.z : f4.w;
        {
          float dd = f - rc0.x, x = f * rc0.x * dd;
          float sel = (dd >= 0.f) ? rc0.z : rc0.w;
          float e = __builtin_amdgcn_exp2f(fmaf(rc0.y, S[kg][0][r], fmaf(x, sel, -sh0)));
          if (kg & 1) ps0a += e; else ps0b += e;
          S[kg][0][r] = e;
        }
        {
          float dd = f - rc1.x, x = f * rc1.x * dd;
          float sel = (dd >= 0.f) ? rc1.z : rc1.w;
          float e = __builtin_amdgcn_exp2f(fmaf(rc1.y, S[kg][1][r], fmaf(x, sel, -sh1)));
          if (kg & 1) ps1a += e; else ps1b += e;
          S[kg][1][r] = e;
        }
      }
    }

    __builtin_amdgcn_s_setprio(1);
    #pragma unroll
    for (int ks = 0; ks < 4; ++ks) {
      union AW { unsigned u[4]; bf16x8 v; } aw0, aw1;
      #pragma unroll
      for (int m = 0; m < 4; ++m) {
        int kg2 = 2 * ks + (m >> 1), rr = (m & 1) * 2;
        unsigned a0 = __float_as_uint(S[kg2][0][rr]), a1 = __float_as_uint(S[kg2][0][rr + 1]);
        aw0.u[m] = ((a1 + 0x8000u) & 0xFFFF0000u) | ((a0 + 0x8000u) >> 16);
        unsigned b0 = __float_as_uint(S[kg2][1][rr]), b1 = __float_as_uint(S[kg2][1][rr + 1]);
        aw1.u[m] = ((b1 + 0x8000u) & 0xFFFF0000u) | ((b0 + 0x8000u) >> 16);
      }
      #pragma unroll
      for (int db = 0; db < 4; ++db) {
        int d = db * 16 + c;
        bf16x8 bv = *(const bf16x8*)(vb_ + d * 128 + (((ks * 4 + g) ^ c) * 8));
        acc[0][db] = __builtin_amdgcn_mfma_f32_16x16x32_bf16(aw0.v, bv, acc[0][db], 0, 0, 0);
        acc[1][db] = __builtin_amdgcn_mfma_f32_16x16x32_bf16(aw1.v, bv, acc[1][db], 0, 0, 0);
      }
    }
    __builtin_amdgcn_s_setprio(0);
  }

  float ps0 = ps0a + ps0b, ps1 = ps1a + ps1b;
  ps0 += __shfl_xor(ps0, 16); ps0 += __shfl_xor(ps0, 32);
  ps1 += __shfl_xor(ps1, 16); ps1 += __shfl_xor(ps1, 32);
  if (g == 0) { psumW[w * 32 + c] = ps0; psumW[w * 32 + 16 + c] = ps1; }

  #pragma unroll
  for (int qh = 0; qh < 2; ++qh)
    #pragma unroll
    for (int r = 0; r < 4; ++r) {
      float rcp = 1.f / psumW[w * 32 + qh * 16 + g * 4 + r];
      int qg = t0 + w * 32 + qh * 16 + g * 4 + r;
      unsigned short* orow = attnO + (size_t)(b * 1024 + qg) * 512 + h * 64 + c;
      #pragma unroll
      for (int db = 0; db < 4; ++db)
        orow[db * 16] = f2bf(acc[qh][db][r] * rcp);
    }
}

extern "C" void kernel_launch(void* const* d_in, const int* in_sizes, int n_in,
                              void* d_out, int out_size, void* d_ws, size_t ws_size,
                              hipStream_t stream) {
  const float* q = (const float*)d_in[0];
  const float* k = (const float*)d_in[1];
  const float* v = (const float*)d_in[2];
  const float* frac = (const float*)d_in[3];
  const float* Wq = (const float*)d_in[4];
  const float* bq = (const float*)d_in[5];
  const float* Wk = (const float*)d_in[6];
  const float* bk = (const float*)d_in[7];
  const float* Wv = (const float*)d_in[8];
  const float* bv = (const float*)d_in[9];
  const float* Wo = (const float*)d_in[10];
  const float* bo = (const float*)d_in[11];
  const float* ap = (const float*)d_in[12];
  const float* an = (const float*)d_in[13];
  const float* gm = (const float*)d_in[14];
  const float* dl = (const float*)d_in[15];
  const int* afb = (const int*)d_in[16];

  char* ws = (char*)d_ws;
  unsigned short* wqT = (unsigned short*)(ws + 0);
  unsigned short* wkT = (unsigned short*)(ws + 524288);
  unsigned short* wvT = (unsigned short*)(ws + 1048576);
  unsigned short* woT = (unsigned short*)(ws + 1572864);
  unsigned short* Qh = (unsigned short*)(ws + 2097152);
  unsigned short* Kh = (unsigned short*)(ws + 10485760);
  unsigned short* Ktr = (unsigned short*)(ws + 18874368);
  unsigned short* Vt = (unsigned short*)(ws + 27262976);
  unsigned short* aO = (unsigned short*)(ws + 35651584);
  float* fst = (float*)(ws + 44040192);
  unsigned short* Mhi = (unsigned short*)(ws + 44171264);
  unsigned short* Mlo = (unsigned short*)(ws + 44695552);
  float* KsumG = (float*)(ws + 45219840);
  float4* rowcG = (float4*)(ws + 45236224);
  float* rowShG = (float*)(ws + 46284800);

  hipFuncSetAttribute((const void*)flash_kernel,
                      hipFuncAttributeMaxDynamicSharedMemorySize, FLASH_SMEM);

  prep_kernel<<<3072, 256, 0, stream>>>(Wq, Wk, Wv, Wo, wqT, wkT, wvT, woT, frac, fst);
  qkv_gemm_kernel<<<768, 256, 0, stream>>>(q, k, v, wqT, wkT, wvT,
                                           bq, bk, bv, Qh, Kh, Ktr, Vt);
  gram_kernel<<<64, 256, 0, stream>>>(Ktr, Mhi, Mlo, KsumG);
  coef_kernel<<<dim3(16, 64), 256, 0, stream>>>(Qh, Mhi, Mlo, KsumG, frac, fst,
                                                ap, an, gm, dl, afb, rowcG, rowShG);
  flash_kernel<<<512, 256, FLASH_SMEM, stream>>>(Qh, Kh, Vt, aO, frac, rowcG, rowShG);
  gemm_out_kernel<<<256, 256, 0, stream>>>(aO, woT, bo, (float*)d_out);
}

// Round 18
// 121.272 us; speedup vs baseline: 1.5468x; 1.0331x over previous
//
#include <hip/hip_runtime.h>
#include <hip/hip_bf16.h>

#define EPS 1e-5f
#define FLASH_SMEM 72704

typedef short bf16x8 __attribute__((ext_vector_type(8)));
typedef float f32x4 __attribute__((ext_vector_type(4)));

#define GL16(gp, lp) __builtin_amdgcn_global_load_lds( \
    (const __attribute__((address_space(1))) void*)(gp), \
    (__attribute__((address_space(3))) void*)(lp), 16, 0, 0)

__device__ __forceinline__ unsigned short f2bf(float f) {
  union { float f; unsigned u; } v; v.f = f;
  return (unsigned short)((v.u + 0x7FFFu + ((v.u >> 16) & 1u)) >> 16);
}
__device__ __forceinline__ float bf2f(unsigned short u) {
  return __uint_as_float(((unsigned)u) << 16);
}

// ---------------- merged prep: 4 weight transposes + frac stats in one launch ----------------
__global__ void prep_kernel(const float* __restrict__ W0, const float* __restrict__ W1,
                            const float* __restrict__ W2, const float* __restrict__ W3,
                            unsigned short* __restrict__ T0, unsigned short* __restrict__ T1,
                            unsigned short* __restrict__ T2, unsigned short* __restrict__ T3,
                            const float* __restrict__ frac, float* __restrict__ fstats) {
  __shared__ float tile[32][33];
  const int L = blockIdx.x;
  if (L < 1024) {
    int z = L >> 8, rem = L & 255;
    const float* W = z == 0 ? W0 : z == 1 ? W1 : z == 2 ? W2 : W3;
    unsigned short* Wt = z == 0 ? T0 : z == 1 ? T1 : z == 2 ? T2 : T3;
    float scale = (z == 0) ? 0.125f : 1.0f;
    int n0 = (rem & 15) * 32, k0 = (rem >> 4) * 32;
    int c = threadIdx.x & 31, r0 = threadIdx.x >> 5;
    #pragma unroll
    for (int rr = 0; rr < 32; rr += 8)
      tile[r0 + rr][c] = W[(k0 + r0 + rr) * 512 + n0 + c];
    __syncthreads();
    #pragma unroll
    for (int rr = 0; rr < 32; rr += 8)
      Wt[(n0 + r0 + rr) * 512 + k0 + c] = f2bf(tile[c][r0 + rr] * scale);
  } else {
    int wid = (int)(((L - 1024) * 256 + threadIdx.x) >> 6);
    int ln = threadIdx.x & 63;
    int b = wid >> 10, q = wid & 1023;
    const float* fr = frac + b * 1024;
    float fq = fr[q];
    float sp = 0.f, sn = 0.f, sp2 = 0.f, sn2 = 0.f;
    for (int i = ln; i < 1024; i += 64) {
      float f = fr[i];
      float dm = (f - fq) * (fq * f);
      float p = fmaxf(dm, 0.f), nn = fminf(dm, 0.f);
      sp += p; sn += nn; sp2 += p * p; sn2 += nn * nn;
    }
    #pragma unroll
    for (int m = 32; m; m >>= 1) {
      sp += __shfl_xor(sp, m); sn += __shfl_xor(sn, m);
      sp2 += __shfl_xor(sp2, m); sn2 += __shfl_xor(sn2, m);
    }
    if (ln == 0) {
      float4 o; o.x = sp; o.y = sn; o.z = sp2; o.w = sn2;
      *(float4*)(fstats + (size_t)wid * 4) = o;
    }
  }
}

// ---------------- fused QKV GEMM (round-14 proven): 128-row tiles, panel swizzle ----------------
__global__ __launch_bounds__(256) void qkv_gemm_kernel(
    const float* __restrict__ Aq, const float* __restrict__ Ak, const float* __restrict__ Av,
    const unsigned short* __restrict__ WqT, const unsigned short* __restrict__ WkT,
    const unsigned short* __restrict__ WvT,
    const float* __restrict__ bq, const float* __restrict__ bk, const float* __restrict__ bv,
    unsigned short* __restrict__ Qh, unsigned short* __restrict__ Kh,
    unsigned short* __restrict__ Ktr, unsigned short* __restrict__ Vt) {
  __shared__ unsigned short Al[2][128 * 32];
  __shared__ unsigned short Bl[2][128 * 32];
  const int L = blockIdx.x;
  const int xcd = L & 7, sl = L >> 3;
  const int xb = sl & 3;
  const int P = (sl >> 2) * 8 + xcd;
  const int yb = P & 63, z = P >> 6;

  const float* A = z == 0 ? Aq : z == 1 ? Ak : Av;
  const unsigned short* Bt = z == 0 ? WqT : z == 1 ? WkT : WvT;
  const float* bias = z == 0 ? bq : z == 1 ? bk : bv;
  const float bscale = (z == 0) ? 0.125f : 1.0f;

  const int tid = threadIdx.x, ln = tid & 63, wv = tid >> 6;
  const int m0 = yb * 128, n0 = xb * 128;
  const int wr = wv >> 1, wc = wv & 1;
  const int arow = tid >> 1;
  const int agh = (tid & 1) * 2;

  auto stageB = [&](int kt, int buf) {
    int kb = kt * 32;
    #pragma unroll
    for (int u = 0; u < 2; ++u) {
      int n = tid + u * 256;
      int Lrow = n >> 2, kcs = n & 3;
      int kc = kcs ^ (Lrow & 3);
      GL16(Bt + (size_t)(n0 + Lrow) * 512 + kb + kc * 8, &Bl[buf][n * 8]);
    }
  };
  auto loadA = [&](int kt, float4* la) {
    const float* src = A + (size_t)(m0 + arow) * 512 + kt * 32 + agh * 8;
    la[0] = *(const float4*)(src);
    la[1] = *(const float4*)(src + 4);
    la[2] = *(const float4*)(src + 8);
    la[3] = *(const float4*)(src + 12);
  };
  auto writeA = [&](int buf, const float4* la) {
    #pragma unroll
    for (int G = 0; G < 2; ++G) {
      union { bf16x8 v; unsigned short u[8]; } pk;
      float4 a = la[2 * G], b2 = la[2 * G + 1];
      pk.u[0] = f2bf(a.x); pk.u[1] = f2bf(a.y); pk.u[2] = f2bf(a.z); pk.u[3] = f2bf(a.w);
      pk.u[4] = f2bf(b2.x); pk.u[5] = f2bf(b2.y); pk.u[6] = f2bf(b2.z); pk.u[7] = f2bf(b2.w);
      int dg = (agh + G) ^ (arow & 3);
      *(bf16x8*)(&Al[buf][arow * 32 + dg * 8]) = pk.v;
    }
  };

  f32x4 acc[4][4] = {};
  float4 la[4];
  loadA(0, la); writeA(0, la);
  stageB(0, 0);
  for (int kt = 0; kt < 16; ++kt) {
    __syncthreads();
    if (kt < 15) { loadA(kt + 1, la); stageB(kt + 1, (kt + 1) & 1); }
    const unsigned short* a_ = Al[kt & 1];
    const unsigned short* b_ = Bl[kt & 1];
    const int kc = ln >> 4;
    bf16x8 afr[4], bfr[4];
    #pragma unroll
    for (int m = 0; m < 4; ++m) {
      int r = wr * 64 + m * 16 + (ln & 15);
      afr[m] = *(const bf16x8*)(a_ + r * 32 + ((kc ^ (r & 3)) * 8));
    }
    #pragma unroll
    for (int n = 0; n < 4; ++n) {
      int r = wc * 64 + n * 16 + (ln & 15);
      bfr[n] = *(const bf16x8*)(b_ + r * 32 + ((kc ^ (r & 3)) * 8));
    }
    #pragma unroll
    for (int m = 0; m < 4; ++m)
      #pragma unroll
      for (int n = 0; n < 4; ++n)
        acc[m][n] = __builtin_amdgcn_mfma_f32_16x16x32_bf16(afr[m], bfr[n], acc[m][n], 0, 0, 0);
    if (kt < 15) writeA((kt + 1) & 1, la);
  }

  #pragma unroll
  for (int m = 0; m < 4; ++m) {
    #pragma unroll
    for (int n = 0; n < 4; ++n) {
      int gm0 = m0 + wr * 64 + m * 16 + (ln >> 4) * 4;
      int gn = n0 + wc * 64 + n * 16 + (ln & 15);
      float bvv = bias[gn] * bscale;
      int hh = gn >> 6, d = gn & 63;
      if (z < 2) {
        unsigned short* o = z == 0 ? Qh : Kh;
        #pragma unroll
        for (int i = 0; i < 4; ++i) {
          int gm = gm0 + i;
          int bb = gm >> 10, t = gm & 1023;
          o[(size_t)((bb * 8 + hh) * 1024 + t) * 64 + d] = f2bf(acc[m][n][i] + bvv);
        }
        if (z == 1) {
          int bb = gm0 >> 10, t = gm0 & 1023;
          ushort4 pk;
          pk.x = f2bf(acc[m][n][0] + bvv);
          pk.y = f2bf(acc[m][n][1] + bvv);
          pk.z = f2bf(acc[m][n][2] + bvv);
          pk.w = f2bf(acc[m][n][3] + bvv);
          *(ushort4*)(Ktr + (size_t)((bb * 8 + hh) * 64 + d) * 1024 + t) = pk;
        }
      } else {
        int bb = gm0 >> 10, t = gm0 & 1023;
        int k5 = t & 31;
        int pos = (t & ~31) + ((k5 >> 2) & 3) * 8 + ((k5 >> 4) & 1) * 4;
        ushort4 pk;
        pk.x = f2bf(acc[m][n][0] + bvv);
        pk.y = f2bf(acc[m][n][1] + bvv);
        pk.z = f2bf(acc[m][n][2] + bvv);
        pk.w = f2bf(acc[m][n][3] + bvv);
        *(ushort4*)(Vt + (size_t)((bb * 8 + hh) * 64 + d) * 1024 + pos) = pk;
      }
    }
  }
}

// ---------------- final GEMM (XCD-panel-swizzled grid) ----------------
__global__ __launch_bounds__(256) void gemm_out_kernel(
    const unsigned short* __restrict__ A,
    const unsigned short* __restrict__ Bt,
    const float* __restrict__ bias,
    float* __restrict__ out) {
  __shared__ unsigned short Al[2][128 * 32];
  __shared__ unsigned short Bl[2][128 * 32];
  const int L = blockIdx.x;
  const int xcd = L & 7, sl = L >> 3;
  const int xb = sl & 3, yb = (sl >> 2) * 8 + xcd;
  const int tid = threadIdx.x, ln = tid & 63, wv = tid >> 6;
  const int m0 = yb * 128, n0 = xb * 128;
  const int wr = wv >> 1, wc = wv & 1;

  auto stage = [&](int kt, int buf) {
    int kb = kt * 32;
    #pragma unroll
    for (int u = 0; u < 2; ++u) {
      int n = tid + u * 256;
      int Lrow = n >> 2, kcs = n & 3;
      int kc = kcs ^ (Lrow & 3);
      GL16(A + (size_t)(m0 + Lrow) * 512 + kb + kc * 8, &Al[buf][n * 8]);
      GL16(Bt + (size_t)(n0 + Lrow) * 512 + kb + kc * 8, &Bl[buf][n * 8]);
    }
  };

  f32x4 acc[4][4] = {};
  stage(0, 0);
  for (int kt = 0; kt < 16; ++kt) {
    __syncthreads();
    if (kt < 15) stage(kt + 1, (kt + 1) & 1);
    const unsigned short* a_ = Al[kt & 1];
    const unsigned short* b_ = Bl[kt & 1];
    const int kc = ln >> 4;
    bf16x8 afr[4], bfr[4];
    #pragma unroll
    for (int m = 0; m < 4; ++m) {
      int r = wr * 64 + m * 16 + (ln & 15);
      afr[m] = *(const bf16x8*)(a_ + r * 32 + ((kc ^ (r & 3)) * 8));
    }
    #pragma unroll
    for (int n = 0; n < 4; ++n) {
      int r = wc * 64 + n * 16 + (ln & 15);
      bfr[n] = *(const bf16x8*)(b_ + r * 32 + ((kc ^ (r & 3)) * 8));
    }
    #pragma unroll
    for (int m = 0; m < 4; ++m)
      #pragma unroll
      for (int n = 0; n < 4; ++n)
        acc[m][n] = __builtin_amdgcn_mfma_f32_16x16x32_bf16(afr[m], bfr[n], acc[m][n], 0, 0, 0);
  }
  #pragma unroll
  for (int m = 0; m < 4; ++m)
    #pragma unroll
    for (int n = 0; n < 4; ++n) {
      int gm0 = m0 + wr * 64 + m * 16 + (ln >> 4) * 4;
      int gn = n0 + wc * 64 + n * 16 + (ln & 15);
      float bvv = bias[gn];
      #pragma unroll
      for (int i = 0; i < 4; ++i)
        out[(size_t)(gm0 + i) * 512 + gn] = acc[m][n][i] + bvv;
    }
}

// ---------------- Gram: M = K^T K split bf16 hi/lo + Ksum per (b,h) ----------------
__global__ __launch_bounds__(256, 1) void gram_kernel(
    const unsigned short* __restrict__ Ktr,
    unsigned short* __restrict__ Mhi, unsigned short* __restrict__ Mlo,
    float* __restrict__ KsumG) {
  __shared__ float KsR[4][64];
  const int bh = blockIdx.x;
  const unsigned short* Kb = Ktr + (size_t)bh * 65536;
  const int tid = threadIdx.x, ln = tid & 63, w = tid >> 6;
  const int c = ln & 15, g = ln >> 4;

  f32x4 acc[4] = {};
  #pragma unroll 2
  for (int kk = 0; kk < 32; ++kk) {
    bf16x8 af = *(const bf16x8*)(Kb + (size_t)(w * 16 + c) * 1024 + kk * 32 + g * 8);
    #pragma unroll
    for (int jt = 0; jt < 4; ++jt) {
      bf16x8 bf = *(const bf16x8*)(Kb + (size_t)(jt * 16 + c) * 1024 + kk * 32 + g * 8);
      acc[jt] = __builtin_amdgcn_mfma_f32_16x16x32_bf16(af, bf, acc[jt], 0, 0, 0);
    }
  }
  #pragma unroll
  for (int jt = 0; jt < 4; ++jt)
    #pragma unroll
    for (int r = 0; r < 4; ++r) {
      float v = acc[jt][r];
      unsigned short hi = f2bf(v);
      unsigned short lo = f2bf(v - bf2f(hi));
      size_t idx = (size_t)bh * 4096 + (w * 16 + g * 4 + r) * 64 + jt * 16 + c;
      Mhi[idx] = hi;
      Mlo[idx] = lo;
    }

  int d = tid & 63, seg = tid >> 6;
  float s = 0.f;
  for (int u = 0; u < 32; ++u) {
    bf16x8 v8 = *(const bf16x8*)(Kb + (size_t)d * 1024 + seg * 256 + u * 8);
    #pragma unroll
    for (int e = 0; e < 8; ++e) s += bf2f((unsigned short)v8[e]);
  }
  KsR[seg][d] = s;
  __syncthreads();
  if (tid < 64)
    KsumG[bh * 64 + tid] = KsR[0][tid] + KsR[1][tid] + KsR[2][tid] + KsR[3][tid];
}

// ---------------- flash with fused coef: (bh,128q)/block, 4 waves x 32q ----------------
__global__ __launch_bounds__(256, 2) void flash_kernel(
    const unsigned short* __restrict__ Qh,
    const unsigned short* __restrict__ Kh,
    const unsigned short* __restrict__ Vt,
    unsigned short* __restrict__ attnO,
    const float* __restrict__ frac,
    const unsigned short* __restrict__ Mhi, const unsigned short* __restrict__ Mlo,
    const float* __restrict__ KsumG, const float* __restrict__ fstats,
    const float* __restrict__ alpha_pos, const float* __restrict__ alpha_neg,
    const float* __restrict__ gamma_p, const float* __restrict__ delta_p,
    const int* __restrict__ afb_p) {
  extern __shared__ char smem[];
  unsigned short* Kl = (unsigned short*)smem;
  unsigned short* Vl = (unsigned short*)(smem + 32768);
  float* fk = (float*)(smem + 65536);
  float4* rowcS = (float4*)(smem + 69632);
  float* rowShS = (float*)(smem + 71680);
  float* psumW = (float*)(smem + 72192);

  const int L = blockIdx.x;
  const int xcd = L & 7, s = L >> 3;
  const int bh = xcd + 8 * (s >> 3);
  const int t0 = (s & 7) * 128;
  const int b = bh >> 3, h = bh & 7;
  const int tid = threadIdx.x, ln = tid & 63, w = tid >> 6;
  const int c = ln & 15, g = ln >> 4;

  auto stageK = [&](int t, int buf) {
    #pragma unroll
    for (int u = 0; u < 4; ++u) {
      int n = tid + u * 256;
      int row = n >> 3, kc = (n & 7) ^ (row & 7);
      GL16(Kh + (size_t)(bh * 1024 + t * 128 + row) * 64 + kc * 8,
           Kl + buf * 8192 + n * 8);
    }
  };
  auto stageV = [&](int t, int buf) {
    #pragma unroll
    for (int u = 0; u < 4; ++u) {
      int n = tid + u * 256;
      int d = n >> 4, ch = n & 15;
      GL16(Vt + (size_t)(bh * 64 + d) * 1024 + t * 128 + (ch ^ (d & 15)) * 8,
           Vl + buf * 8192 + n * 8);
    }
  };

  stageK(0, 0);
  stageV(0, 0);
  GL16(frac + b * 1024 + tid * 4, fk + tid * 4);

  bf16x8 qf[2][2];
  #pragma unroll
  for (int qh = 0; qh < 2; ++qh) {
    const unsigned short* qrow =
        Qh + (size_t)(bh * 1024 + t0 + w * 32 + qh * 16 + c) * 64 + g * 8;
    qf[qh][0] = *(const bf16x8*)(qrow);
    qf[qh][1] = *(const bf16x8*)(qrow + 32);
  }

  // ---- fused coef: this block's 128 rows, 2 passes/wave; qf IS the A-fragment ----
  {
    const float gmv = *gamma_p, dlv = *delta_p;
    const float apv = alpha_pos[h], anv = alpha_neg[h];
    const int afb = *afb_p;
    const float L2E = 1.4426950408889634f;
    const unsigned short* Mh = Mhi + (size_t)bh * 4096;
    const unsigned short* Ml = Mlo + (size_t)bh * 4096;
    float ks[4];
    #pragma unroll
    for (int jt = 0; jt < 4; ++jt) ks[jt] = KsumG[bh * 64 + jt * 16 + c];

    #pragma unroll
    for (int pass = 0; pass < 2; ++pass) {
      const int qrow0 = t0 + w * 32 + pass * 16;
      f32x4 acy[4] = {};
      #pragma unroll
      for (int jt = 0; jt < 4; ++jt) {
        const unsigned short* mrow = Mh + (jt * 16 + c) * 64 + g * 8;
        const unsigned short* lrow = Ml + (jt * 16 + c) * 64 + g * 8;
        bf16x8 mh0 = *(const bf16x8*)(mrow);
        bf16x8 mh1 = *(const bf16x8*)(mrow + 32);
        bf16x8 ml0 = *(const bf16x8*)(lrow);
        bf16x8 ml1 = *(const bf16x8*)(lrow + 32);
        acy[jt] = __builtin_amdgcn_mfma_f32_16x16x32_bf16(qf[pass][0], mh0, acy[jt], 0, 0, 0);
        acy[jt] = __builtin_amdgcn_mfma_f32_16x16x32_bf16(qf[pass][1], mh1, acy[jt], 0, 0, 0);
        acy[jt] = __builtin_amdgcn_mfma_f32_16x16x32_bf16(qf[pass][0], ml0, acy[jt], 0, 0, 0);
        acy[jt] = __builtin_amdgcn_mfma_f32_16x16x32_bf16(qf[pass][1], ml1, acy[jt], 0, 0, 0);
      }
      float pl[4], p2[4];
      #pragma unroll
      for (int r = 0; r < 4; ++r) {
        const unsigned short* qd = Qh + (size_t)(bh * 1024 + qrow0 + g * 4 + r) * 64 + c;
        float l = 0.f, s2 = 0.f;
        #pragma unroll
        for (int jt = 0; jt < 4; ++jt) {
          float qv = bf2f(qd[jt * 16]);
          s2 += qv * acy[jt][r];
          l += qv * ks[jt];
        }
        pl[r] = l; p2[r] = s2;
      }
      #pragma unroll
      for (int m = 1; m < 16; m <<= 1)
        #pragma unroll
        for (int r = 0; r < 4; ++r) {
          pl[r] += __shfl_xor(pl[r], m);
          p2[r] += __shfl_xor(p2[r], m);
        }
      if (c == 0) {
        #pragma unroll
        for (int r = 0; r < 4; ++r) {
          int q = qrow0 + g * 4 + r;                 // global q
          int lq = w * 32 + pass * 16 + g * 4 + r;   // block-local
          float sl = pl[r], sl2 = p2[r];
          float mul_ = sl * (1.f / 1024.f);
          float varl = fmaxf((sl2 - 1024.f * mul_ * mul_) * (1.f / 1023.f), 0.f);
          float cA = gmv / (sqrtf(varl) + EPS);
          float4 st = *(const float4*)(fstats + (size_t)(b * 1024 + q) * 4);
          float msum = apv * st.x + anv * st.y;
          float msq = apv * apv * st.z + anv * anv * st.w;
          float mus = msum * (1.f / 1024.f);
          float vars = fmaxf((msq - 1024.f * mus * mus) * (1.f / 1023.f), 0.f);
          float cB = afb ? (dlv / (sqrtf(vars) + EPS)) : 0.f;
          float4 rc;
          rc.x = frac[b * 1024 + q];
          rc.y = cA * L2E;
          rc.z = cB * apv * L2E;
          rc.w = cB * anv * L2E;
          rowcS[lq] = rc;
          rowShS[lq] = (cA * mul_ + cB * mus) * L2E;
        }
      }
    }
  }
  __syncthreads();   // covers GL16 staging + coef LDS writes

  const float4 rc0 = rowcS[w * 32 + c], rc1 = rowcS[w * 32 + 16 + c];
  const float sh0 = rowShS[w * 32 + c], sh1 = rowShS[w * 32 + 16 + c];

  f32x4 acc[2][4] = {};
  float ps0a = 0.f, ps0b = 0.f, ps1a = 0.f, ps1b = 0.f;

  for (int t = 0; t < 8; ++t) {
    if (t) __syncthreads();
    if (t < 7) { stageK(t + 1, (t + 1) & 1); stageV(t + 1, (t + 1) & 1); }
    const unsigned short* kb_ = Kl + (t & 1) * 8192;
    const unsigned short* vb_ = Vl + (t & 1) * 8192;

    f32x4 S[8][2];
    #pragma unroll
    for (int kg = 0; kg < 8; ++kg) {
      int krow = kg * 16 + c;
      bf16x8 kf0 = *(const bf16x8*)(kb_ + krow * 64 + ((g ^ (krow & 7)) * 8));
      bf16x8 kf1 = *(const bf16x8*)(kb_ + krow * 64 + (((g + 4) ^ (krow & 7)) * 8));
      #pragma unroll
      for (int qh = 0; qh < 2; ++qh) {
        f32x4 a = {0.f, 0.f, 0.f, 0.f};
        a = __builtin_amdgcn_mfma_f32_16x16x32_bf16(kf0, qf[qh][0], a, 0, 0, 0);
        a = __builtin_amdgcn_mfma_f32_16x16x32_bf16(kf1, qf[qh][1], a, 0, 0, 0);
        S[kg][qh] = a;
      }
    }

    #pragma unroll
    for (int kg = 0; kg < 8; ++kg) {
      float4 f4 = *(const float4*)(&fk[t * 128 + kg * 16 + g * 4]);
      #pragma unroll
      for (int r = 0; r < 4; ++r) {
        float f = (r == 0) ? f4.x : (r == 1) ? f4.y : (r == 2) ? f4.z : f4.w;
        {
          float dd = f - rc0.x, x = f * rc0.x * dd;
          float sel = (dd >= 0.f) ? rc0.z : rc0.w;
          float e = __builtin_amdgcn_exp2f(fmaf(rc0.y, S[kg][0][r], fmaf(x, sel, -sh0)));
          if (kg & 1) ps0a += e; else ps0b += e;
          S[kg][0][r] = e;
        }
        {
          float dd = f - rc1.x, x = f * rc1.x * dd;
          float sel = (dd >= 0.f) ? rc1.z : rc1.w;
          float e = __builtin_amdgcn_exp2f(fmaf(rc1.y, S[kg][1][r], fmaf(x, sel, -sh1)));
          if (kg & 1) ps1a += e; else ps1b += e;
          S[kg][1][r] = e;
        }
      }
    }

    __builtin_amdgcn_s_setprio(1);
    #pragma unroll
    for (int ks = 0; ks < 4; ++ks) {
      union AW { unsigned u[4]; bf16x8 v; } aw0, aw1;
      #pragma unroll
      for (int m = 0; m < 4; ++m) {
        int kg2 = 2 * ks + (m >> 1), rr = (m & 1) * 2;
        unsigned a0 = __float_as_uint(S[kg2][0][rr]), a1 = __float_as_uint(S[kg2][0][rr + 1]);
        aw0.u[m] = ((a1 + 0x8000u) & 0xFFFF0000u) | ((a0 + 0x8000u) >> 16);
        unsigned b0 = __float_as_uint(S[kg2][1][rr]), b1 = __float_as_uint(S[kg2][1][rr + 1]);
        aw1.u[m] = ((b1 + 0x8000u) & 0xFFFF0000u) | ((b0 + 0x8000u) >> 16);
      }
      #pragma unroll
      for (int db = 0; db < 4; ++db) {
        int d = db * 16 + c;
        bf16x8 bv = *(const bf16x8*)(vb_ + d * 128 + (((ks * 4 + g) ^ c) * 8));
        acc[0][db] = __builtin_amdgcn_mfma_f32_16x16x32_bf16(aw0.v, bv, acc[0][db], 0, 0, 0);
        acc[1][db] = __builtin_amdgcn_mfma_f32_16x16x32_bf16(aw1.v, bv, acc[1][db], 0, 0, 0);
      }
    }
    __builtin_amdgcn_s_setprio(0);
  }

  float ps0 = ps0a + ps0b, ps1 = ps1a + ps1b;
  ps0 += __shfl_xor(ps0, 16); ps0 += __shfl_xor(ps0, 32);
  ps1 += __shfl_xor(ps1, 16); ps1 += __shfl_xor(ps1, 32);
  if (g == 0) { psumW[w * 32 + c] = ps0; psumW[w * 32 + 16 + c] = ps1; }

  #pragma unroll
  for (int qh = 0; qh < 2; ++qh)
    #pragma unroll
    for (int r = 0; r < 4; ++r) {
      float rcp = 1.f / psumW[w * 32 + qh * 16 + g * 4 + r];
      int qg = t0 + w * 32 + qh * 16 + g * 4 + r;
      unsigned short* orow = attnO + (size_t)(b * 1024 + qg) * 512 + h * 64 + c;
      #pragma unroll
      for (int db = 0; db < 4; ++db)
        orow[db * 16] = f2bf(acc[qh][db][r] * rcp);
    }
}

extern "C" void kernel_launch(void* const* d_in, const int* in_sizes, int n_in,
                              void* d_out, int out_size, void* d_ws, size_t ws_size,
                              hipStream_t stream) {
  const float* q = (const float*)d_in[0];
  const float* k = (const float*)d_in[1];
  const float* v = (const float*)d_in[2];
  const float* frac = (const float*)d_in[3];
  const float* Wq = (const float*)d_in[4];
  const float* bq = (const float*)d_in[5];
  const float* Wk = (const float*)d_in[6];
  const float* bk = (const float*)d_in[7];
  const float* Wv = (const float*)d_in[8];
  const float* bv = (const float*)d_in[9];
  const float* Wo = (const float*)d_in[10];
  const float* bo = (const float*)d_in[11];
  const float* ap = (const float*)d_in[12];
  const float* an = (const float*)d_in[13];
  const float* gm = (const float*)d_in[14];
  const float* dl = (const float*)d_in[15];
  const int* afb = (const int*)d_in[16];

  char* ws = (char*)d_ws;
  unsigned short* wqT = (unsigned short*)(ws + 0);
  unsigned short* wkT = (unsigned short*)(ws + 524288);
  unsigned short* wvT = (unsigned short*)(ws + 1048576);
  unsigned short* woT = (unsigned short*)(ws + 1572864);
  unsigned short* Qh = (unsigned short*)(ws + 2097152);
  unsigned short* Kh = (unsigned short*)(ws + 10485760);
  unsigned short* Ktr = (unsigned short*)(ws + 18874368);
  unsigned short* Vt = (unsigned short*)(ws + 27262976);
  unsigned short* aO = (unsigned short*)(ws + 35651584);
  float* fst = (float*)(ws + 44040192);
  unsigned short* Mhi = (unsigned short*)(ws + 44171264);
  unsigned short* Mlo = (unsigned short*)(ws + 44695552);
  float* KsumG = (float*)(ws + 45219840);

  hipFuncSetAttribute((const void*)flash_kernel,
                      hipFuncAttributeMaxDynamicSharedMemorySize, FLASH_SMEM);

  prep_kernel<<<3072, 256, 0, stream>>>(Wq, Wk, Wv, Wo, wqT, wkT, wvT, woT, frac, fst);
  qkv_gemm_kernel<<<768, 256, 0, stream>>>(q, k, v, wqT, wkT, wvT,
                                           bq, bk, bv, Qh, Kh, Ktr, Vt);
  gram_kernel<<<64, 256, 0, stream>>>(Ktr, Mhi, Mlo, KsumG);
  flash_kernel<<<512, 256, FLASH_SMEM, stream>>>(Qh, Kh, Vt, aO, frac,
                                                 Mhi, Mlo, KsumG, fst,
                                                 ap, an, gm, dl, afb);
  gemm_out_kernel<<<256, 256, 0, stream>>>(aO, woT, bo, (float*)d_out);
}

// Round 19
// 117.862 us; speedup vs baseline: 1.5916x; 1.0289x over previous
//
#include <hip/hip_runtime.h>
#include <hip/hip_bf16.h>

#define EPS 1e-5f
#define FLASH_SMEM 72704

typedef short bf16x8 __attribute__((ext_vector_type(8)));
typedef float f32x4 __attribute__((ext_vector_type(4)));

#define GL16(gp, lp) __builtin_amdgcn_global_load_lds( \
    (const __attribute__((address_space(1))) void*)(gp), \
    (__attribute__((address_space(3))) void*)(lp), 16, 0, 0)

__device__ __forceinline__ unsigned short f2bf(float f) {
  union { float f; unsigned u; } v; v.f = f;
  return (unsigned short)((v.u + 0x7FFFu + ((v.u >> 16) & 1u)) >> 16);
}
__device__ __forceinline__ float bf2f(unsigned short u) {
  return __uint_as_float(((unsigned)u) << 16);
}

// ---------------- merged prep: 4 weight transposes + frac stats in one launch ----------------
__global__ void prep_kernel(const float* __restrict__ W0, const float* __restrict__ W1,
                            const float* __restrict__ W2, const float* __restrict__ W3,
                            unsigned short* __restrict__ T0, unsigned short* __restrict__ T1,
                            unsigned short* __restrict__ T2, unsigned short* __restrict__ T3,
                            const float* __restrict__ frac, float* __restrict__ fstats) {
  __shared__ float tile[32][33];
  const int L = blockIdx.x;
  if (L < 1024) {
    int z = L >> 8, rem = L & 255;
    const float* W = z == 0 ? W0 : z == 1 ? W1 : z == 2 ? W2 : W3;
    unsigned short* Wt = z == 0 ? T0 : z == 1 ? T1 : z == 2 ? T2 : T3;
    float scale = (z == 0) ? 0.125f : 1.0f;
    int n0 = (rem & 15) * 32, k0 = (rem >> 4) * 32;
    int c = threadIdx.x & 31, r0 = threadIdx.x >> 5;
    #pragma unroll
    for (int rr = 0; rr < 32; rr += 8)
      tile[r0 + rr][c] = W[(k0 + r0 + rr) * 512 + n0 + c];
    __syncthreads();
    #pragma unroll
    for (int rr = 0; rr < 32; rr += 8)
      Wt[(n0 + r0 + rr) * 512 + k0 + c] = f2bf(tile[c][r0 + rr] * scale);
  } else {
    int wid = (int)(((L - 1024) * 256 + threadIdx.x) >> 6);
    int ln = threadIdx.x & 63;
    int b = wid >> 10, q = wid & 1023;
    const float* fr = frac + b * 1024;
    float fq = fr[q];
    float sp = 0.f, sn = 0.f, sp2 = 0.f, sn2 = 0.f;
    for (int i = ln; i < 1024; i += 64) {
      float f = fr[i];
      float dm = (f - fq) * (fq * f);
      float p = fmaxf(dm, 0.f), nn = fminf(dm, 0.f);
      sp += p; sn += nn; sp2 += p * p; sn2 += nn * nn;
    }
    #pragma unroll
    for (int m = 32; m; m >>= 1) {
      sp += __shfl_xor(sp, m); sn += __shfl_xor(sn, m);
      sp2 += __shfl_xor(sp2, m); sn2 += __shfl_xor(sn2, m);
    }
    if (ln == 0) {
      float4 o; o.x = sp; o.y = sn; o.z = sp2; o.w = sn2;
      *(float4*)(fstats + (size_t)wid * 4) = o;
    }
  }
}

// ---------------- fused QKV GEMM: A staged as fp32 via GL16 (fire-and-forget), cvt on read ----------------
__global__ __launch_bounds__(256) void qkv_gemm_kernel(
    const float* __restrict__ Aq, const float* __restrict__ Ak, const float* __restrict__ Av,
    const unsigned short* __restrict__ WqT, const unsigned short* __restrict__ WkT,
    const unsigned short* __restrict__ WvT,
    const float* __restrict__ bq, const float* __restrict__ bk, const float* __restrict__ bv,
    unsigned short* __restrict__ Qh, unsigned short* __restrict__ Kh,
    unsigned short* __restrict__ Ktr, unsigned short* __restrict__ Vt) {
  __shared__ float AlF[2][128 * 32];          // 2 x 16 KB fp32
  __shared__ unsigned short Bl[2][128 * 32];  // 2 x 8 KB bf16
  const int L = blockIdx.x;
  const int xcd = L & 7, sl = L >> 3;
  const int xb = sl & 3;
  const int P = (sl >> 2) * 8 + xcd;   // panel id 0..191
  const int yb = P & 63, z = P >> 6;

  const float* A = z == 0 ? Aq : z == 1 ? Ak : Av;
  const unsigned short* Bt = z == 0 ? WqT : z == 1 ? WkT : WvT;
  const float* bias = z == 0 ? bq : z == 1 ? bk : bv;
  const float bscale = (z == 0) ? 0.125f : 1.0f;

  const int tid = threadIdx.x, ln = tid & 63, wv = tid >> 6;
  const int m0 = yb * 128, n0 = xb * 128;
  const int wr = wv >> 1, wc = wv & 1;

  auto stageA = [&](int kt, int buf) {
    #pragma unroll
    for (int u = 0; u < 4; ++u) {
      int n = tid + u * 256;                   // 1024 x 16B = 16 KB
      int row = n >> 3, ch = n & 7;            // 8 chunks of 4 floats per row
      GL16(A + (size_t)(m0 + row) * 512 + kt * 32 + ((ch ^ (row & 7)) * 4),
           &AlF[buf][n * 4]);
    }
  };
  auto stageB = [&](int kt, int buf) {
    int kb = kt * 32;
    #pragma unroll
    for (int u = 0; u < 2; ++u) {
      int n = tid + u * 256;
      int Lrow = n >> 2, kcs = n & 3;
      int kc = kcs ^ (Lrow & 3);
      GL16(Bt + (size_t)(n0 + Lrow) * 512 + kb + kc * 8, &Bl[buf][n * 8]);
    }
  };

  f32x4 acc[4][4] = {};
  stageA(0, 0);
  stageB(0, 0);
  for (int kt = 0; kt < 16; ++kt) {
    __syncthreads();
    if (kt < 15) { stageA(kt + 1, (kt + 1) & 1); stageB(kt + 1, (kt + 1) & 1); }
    const float* a_ = AlF[kt & 1];
    const unsigned short* b_ = Bl[kt & 1];
    const int g = ln >> 4;
    bf16x8 afr[4], bfr[4];
    #pragma unroll
    for (int m = 0; m < 4; ++m) {
      int r = wr * 64 + m * 16 + (ln & 15);
      const float* ar = a_ + r * 32;
      float4 fA = *(const float4*)(ar + (((2 * g) ^ (r & 7)) * 4));
      float4 fB = *(const float4*)(ar + (((2 * g + 1) ^ (r & 7)) * 4));
      union { unsigned u[4]; bf16x8 v; } cv;
      asm("v_cvt_pk_bf16_f32 %0, %1, %2" : "=v"(cv.u[0]) : "v"(fA.x), "v"(fA.y));
      asm("v_cvt_pk_bf16_f32 %0, %1, %2" : "=v"(cv.u[1]) : "v"(fA.z), "v"(fA.w));
      asm("v_cvt_pk_bf16_f32 %0, %1, %2" : "=v"(cv.u[2]) : "v"(fB.x), "v"(fB.y));
      asm("v_cvt_pk_bf16_f32 %0, %1, %2" : "=v"(cv.u[3]) : "v"(fB.z), "v"(fB.w));
      afr[m] = cv.v;
    }
    #pragma unroll
    for (int n = 0; n < 4; ++n) {
      int r = wc * 64 + n * 16 + (ln & 15);
      bfr[n] = *(const bf16x8*)(b_ + r * 32 + ((g ^ (r & 3)) * 8));
    }
    #pragma unroll
    for (int m = 0; m < 4; ++m)
      #pragma unroll
      for (int n = 0; n < 4; ++n)
        acc[m][n] = __builtin_amdgcn_mfma_f32_16x16x32_bf16(afr[m], bfr[n], acc[m][n], 0, 0, 0);
  }

  #pragma unroll
  for (int m = 0; m < 4; ++m) {
    #pragma unroll
    for (int n = 0; n < 4; ++n) {
      int gm0 = m0 + wr * 64 + m * 16 + (ln >> 4) * 4;
      int gn = n0 + wc * 64 + n * 16 + (ln & 15);
      float bvv = bias[gn] * bscale;
      int hh = gn >> 6, d = gn & 63;
      if (z < 2) {
        unsigned short* o = z == 0 ? Qh : Kh;
        #pragma unroll
        for (int i = 0; i < 4; ++i) {
          int gm = gm0 + i;
          int bb = gm >> 10, t = gm & 1023;
          o[(size_t)((bb * 8 + hh) * 1024 + t) * 64 + d] = f2bf(acc[m][n][i] + bvv);
        }
        if (z == 1) {
          int bb = gm0 >> 10, t = gm0 & 1023;
          ushort4 pk;
          pk.x = f2bf(acc[m][n][0] + bvv);
          pk.y = f2bf(acc[m][n][1] + bvv);
          pk.z = f2bf(acc[m][n][2] + bvv);
          pk.w = f2bf(acc[m][n][3] + bvv);
          *(ushort4*)(Ktr + (size_t)((bb * 8 + hh) * 64 + d) * 1024 + t) = pk;
        }
      } else {
        int bb = gm0 >> 10, t = gm0 & 1023;
        int k5 = t & 31;
        int pos = (t & ~31) + ((k5 >> 2) & 3) * 8 + ((k5 >> 4) & 1) * 4;
        ushort4 pk;
        pk.x = f2bf(acc[m][n][0] + bvv);
        pk.y = f2bf(acc[m][n][1] + bvv);
        pk.z = f2bf(acc[m][n][2] + bvv);
        pk.w = f2bf(acc[m][n][3] + bvv);
        *(ushort4*)(Vt + (size_t)((bb * 8 + hh) * 64 + d) * 1024 + pos) = pk;
      }
    }
  }
}

// ---------------- final GEMM (XCD-panel-swizzled grid) ----------------
__global__ __launch_bounds__(256) void gemm_out_kernel(
    const unsigned short* __restrict__ A,
    const unsigned short* __restrict__ Bt,
    const float* __restrict__ bias,
    float* __restrict__ out) {
  __shared__ unsigned short Al[2][128 * 32];
  __shared__ unsigned short Bl[2][128 * 32];
  const int L = blockIdx.x;
  const int xcd = L & 7, sl = L >> 3;
  const int xb = sl & 3, yb = (sl >> 2) * 8 + xcd;
  const int tid = threadIdx.x, ln = tid & 63, wv = tid >> 6;
  const int m0 = yb * 128, n0 = xb * 128;
  const int wr = wv >> 1, wc = wv & 1;

  auto stage = [&](int kt, int buf) {
    int kb = kt * 32;
    #pragma unroll
    for (int u = 0; u < 2; ++u) {
      int n = tid + u * 256;
      int Lrow = n >> 2, kcs = n & 3;
      int kc = kcs ^ (Lrow & 3);
      GL16(A + (size_t)(m0 + Lrow) * 512 + kb + kc * 8, &Al[buf][n * 8]);
      GL16(Bt + (size_t)(n0 + Lrow) * 512 + kb + kc * 8, &Bl[buf][n * 8]);
    }
  };

  f32x4 acc[4][4] = {};
  stage(0, 0);
  for (int kt = 0; kt < 16; ++kt) {
    __syncthreads();
    if (kt < 15) stage(kt + 1, (kt + 1) & 1);
    const unsigned short* a_ = Al[kt & 1];
    const unsigned short* b_ = Bl[kt & 1];
    const int kc = ln >> 4;
    bf16x8 afr[4], bfr[4];
    #pragma unroll
    for (int m = 0; m < 4; ++m) {
      int r = wr * 64 + m * 16 + (ln & 15);
      afr[m] = *(const bf16x8*)(a_ + r * 32 + ((kc ^ (r & 3)) * 8));
    }
    #pragma unroll
    for (int n = 0; n < 4; ++n) {
      int r = wc * 64 + n * 16 + (ln & 15);
      bfr[n] = *(const bf16x8*)(b_ + r * 32 + ((kc ^ (r & 3)) * 8));
    }
    #pragma unroll
    for (int m = 0; m < 4; ++m)
      #pragma unroll
      for (int n = 0; n < 4; ++n)
        acc[m][n] = __builtin_amdgcn_mfma_f32_16x16x32_bf16(afr[m], bfr[n], acc[m][n], 0, 0, 0);
  }
  #pragma unroll
  for (int m = 0; m < 4; ++m)
    #pragma unroll
    for (int n = 0; n < 4; ++n) {
      int gm0 = m0 + wr * 64 + m * 16 + (ln >> 4) * 4;
      int gn = n0 + wc * 64 + n * 16 + (ln & 15);
      float bvv = bias[gn];
      #pragma unroll
      for (int i = 0; i < 4; ++i)
        out[(size_t)(gm0 + i) * 512 + gn] = acc[m][n][i] + bvv;
    }
}

// ---------------- Gram: M = K^T K split bf16 hi/lo + Ksum per (b,h) ----------------
__global__ __launch_bounds__(256, 1) void gram_kernel(
    const unsigned short* __restrict__ Ktr,
    unsigned short* __restrict__ Mhi, unsigned short* __restrict__ Mlo,
    float* __restrict__ KsumG) {
  __shared__ float KsR[4][64];
  const int bh = blockIdx.x;
  const unsigned short* Kb = Ktr + (size_t)bh * 65536;
  const int tid = threadIdx.x, ln = tid & 63, w = tid >> 6;
  const int c = ln & 15, g = ln >> 4;

  f32x4 acc[4] = {};
  #pragma unroll 2
  for (int kk = 0; kk < 32; ++kk) {
    bf16x8 af = *(const bf16x8*)(Kb + (size_t)(w * 16 + c) * 1024 + kk * 32 + g * 8);
    #pragma unroll
    for (int jt = 0; jt < 4; ++jt) {
      bf16x8 bf = *(const bf16x8*)(Kb + (size_t)(jt * 16 + c) * 1024 + kk * 32 + g * 8);
      acc[jt] = __builtin_amdgcn_mfma_f32_16x16x32_bf16(af, bf, acc[jt], 0, 0, 0);
    }
  }
  #pragma unroll
  for (int jt = 0; jt < 4; ++jt)
    #pragma unroll
    for (int r = 0; r < 4; ++r) {
      float v = acc[jt][r];
      unsigned short hi = f2bf(v);
      unsigned short lo = f2bf(v - bf2f(hi));
      size_t idx = (size_t)bh * 4096 + (w * 16 + g * 4 + r) * 64 + jt * 16 + c;
      Mhi[idx] = hi;
      Mlo[idx] = lo;
    }

  int d = tid & 63, seg = tid >> 6;
  float s = 0.f;
  for (int u = 0; u < 32; ++u) {
    bf16x8 v8 = *(const bf16x8*)(Kb + (size_t)d * 1024 + seg * 256 + u * 8);
    #pragma unroll
    for (int e = 0; e < 8; ++e) s += bf2f((unsigned short)v8[e]);
  }
  KsR[seg][d] = s;
  __syncthreads();
  if (tid < 64)
    KsumG[bh * 64 + tid] = KsR[0][tid] + KsR[1][tid] + KsR[2][tid] + KsR[3][tid];
}

// ---------------- flash with fused coef: (bh,128q)/block, 4 waves x 32q ----------------
__global__ __launch_bounds__(256, 2) void flash_kernel(
    const unsigned short* __restrict__ Qh,
    const unsigned short* __restrict__ Kh,
    const unsigned short* __restrict__ Vt,
    unsigned short* __restrict__ attnO,
    const float* __restrict__ frac,
    const unsigned short* __restrict__ Mhi, const unsigned short* __restrict__ Mlo,
    const float* __restrict__ KsumG, const float* __restrict__ fstats,
    const float* __restrict__ alpha_pos, const float* __restrict__ alpha_neg,
    const float* __restrict__ gamma_p, const float* __restrict__ delta_p,
    const int* __restrict__ afb_p) {
  extern __shared__ char smem[];
  unsigned short* Kl = (unsigned short*)smem;
  unsigned short* Vl = (unsigned short*)(smem + 32768);
  float* fk = (float*)(smem + 65536);
  float4* rowcS = (float4*)(smem + 69632);
  float* rowShS = (float*)(smem + 71680);
  float* psumW = (float*)(smem + 72192);

  const int L = blockIdx.x;
  const int xcd = L & 7, s = L >> 3;
  const int bh = xcd + 8 * (s >> 3);
  const int t0 = (s & 7) * 128;
  const int b = bh >> 3, h = bh & 7;
  const int tid = threadIdx.x, ln = tid & 63, w = tid >> 6;
  const int c = ln & 15, g = ln >> 4;

  auto stageK = [&](int t, int buf) {
    #pragma unroll
    for (int u = 0; u < 4; ++u) {
      int n = tid + u * 256;
      int row = n >> 3, kc = (n & 7) ^ (row & 7);
      GL16(Kh + (size_t)(bh * 1024 + t * 128 + row) * 64 + kc * 8,
           Kl + buf * 8192 + n * 8);
    }
  };
  auto stageV = [&](int t, int buf) {
    #pragma unroll
    for (int u = 0; u < 4; ++u) {
      int n = tid + u * 256;
      int d = n >> 4, ch = n & 15;
      GL16(Vt + (size_t)(bh * 64 + d) * 1024 + t * 128 + (ch ^ (d & 15)) * 8,
           Vl + buf * 8192 + n * 8);
    }
  };

  stageK(0, 0);
  stageV(0, 0);
  GL16(frac + b * 1024 + tid * 4, fk + tid * 4);

  bf16x8 qf[2][2];
  #pragma unroll
  for (int qh = 0; qh < 2; ++qh) {
    const unsigned short* qrow =
        Qh + (size_t)(bh * 1024 + t0 + w * 32 + qh * 16 + c) * 64 + g * 8;
    qf[qh][0] = *(const bf16x8*)(qrow);
    qf[qh][1] = *(const bf16x8*)(qrow + 32);
  }

  // ---- fused coef: this block's 128 rows, 2 passes/wave; qf IS the A-fragment ----
  {
    const float gmv = *gamma_p, dlv = *delta_p;
    const float apv = alpha_pos[h], anv = alpha_neg[h];
    const int afb = *afb_p;
    const float L2E = 1.4426950408889634f;
    const unsigned short* Mh = Mhi + (size_t)bh * 4096;
    const unsigned short* Ml = Mlo + (size_t)bh * 4096;
    float ks[4];
    #pragma unroll
    for (int jt = 0; jt < 4; ++jt) ks[jt] = KsumG[bh * 64 + jt * 16 + c];

    #pragma unroll
    for (int pass = 0; pass < 2; ++pass) {
      const int qrow0 = t0 + w * 32 + pass * 16;
      f32x4 acy[4] = {};
      #pragma unroll
      for (int jt = 0; jt < 4; ++jt) {
        const unsigned short* mrow = Mh + (jt * 16 + c) * 64 + g * 8;
        const unsigned short* lrow = Ml + (jt * 16 + c) * 64 + g * 8;
        bf16x8 mh0 = *(const bf16x8*)(mrow);
        bf16x8 mh1 = *(const bf16x8*)(mrow + 32);
        bf16x8 ml0 = *(const bf16x8*)(lrow);
        bf16x8 ml1 = *(const bf16x8*)(lrow + 32);
        acy[jt] = __builtin_amdgcn_mfma_f32_16x16x32_bf16(qf[pass][0], mh0, acy[jt], 0, 0, 0);
        acy[jt] = __builtin_amdgcn_mfma_f32_16x16x32_bf16(qf[pass][1], mh1, acy[jt], 0, 0, 0);
        acy[jt] = __builtin_amdgcn_mfma_f32_16x16x32_bf16(qf[pass][0], ml0, acy[jt], 0, 0, 0);
        acy[jt] = __builtin_amdgcn_mfma_f32_16x16x32_bf16(qf[pass][1], ml1, acy[jt], 0, 0, 0);
      }
      float pl[4], p2[4];
      #pragma unroll
      for (int r = 0; r < 4; ++r) {
        const unsigned short* qd = Qh + (size_t)(bh * 1024 + qrow0 + g * 4 + r) * 64 + c;
        float l = 0.f, s2 = 0.f;
        #pragma unroll
        for (int jt = 0; jt < 4; ++jt) {
          float qv = bf2f(qd[jt * 16]);
          s2 += qv * acy[jt][r];
          l += qv * ks[jt];
        }
        pl[r] = l; p2[r] = s2;
      }
      #pragma unroll
      for (int m = 1; m < 16; m <<= 1)
        #pragma unroll
        for (int r = 0; r < 4; ++r) {
          pl[r] += __shfl_xor(pl[r], m);
          p2[r] += __shfl_xor(p2[r], m);
        }
      if (c == 0) {
        #pragma unroll
        for (int r = 0; r < 4; ++r) {
          int q = qrow0 + g * 4 + r;
          int lq = w * 32 + pass * 16 + g * 4 + r;
          float sl = pl[r], sl2 = p2[r];
          float mul_ = sl * (1.f / 1024.f);
          float varl = fmaxf((sl2 - 1024.f * mul_ * mul_) * (1.f / 1023.f), 0.f);
          float cA = gmv / (sqrtf(varl) + EPS);
          float4 st = *(const float4*)(fstats + (size_t)(b * 1024 + q) * 4);
          float msum = apv * st.x + anv * st.y;
          float msq = apv * apv * st.z + anv * anv * st.w;
          float mus = msum * (1.f / 1024.f);
          float vars = fmaxf((msq - 1024.f * mus * mus) * (1.f / 1023.f), 0.f);
          float cB = afb ? (dlv / (sqrtf(vars) + EPS)) : 0.f;
          float4 rc;
          rc.x = frac[b * 1024 + q];
          rc.y = cA * L2E;
          rc.z = cB * apv * L2E;
          rc.w = cB * anv * L2E;
          rowcS[lq] = rc;
          rowShS[lq] = (cA * mul_ + cB * mus) * L2E;
        }
      }
    }
  }
  __syncthreads();

  const float4 rc0 = rowcS[w * 32 + c], rc1 = rowcS[w * 32 + 16 + c];
  const float sh0 = rowShS[w * 32 + c], sh1 = rowShS[w * 32 + 16 + c];

  f32x4 acc[2][4] = {};
  float ps0a = 0.f, ps0b = 0.f, ps1a = 0.f, ps1b = 0.f;

  for (int t = 0; t < 8; ++t) {
    if (t) __syncthreads();
    if (t < 7) { stageK(t + 1, (t + 1) & 1); stageV(t + 1, (t + 1) & 1); }
    const unsigned short* kb_ = Kl + (t & 1) * 8192;
    const unsigned short* vb_ = Vl + (t & 1) * 8192;

    f32x4 S[8][2];
    #pragma unroll
    for (int kg = 0; kg < 8; ++kg) {
      int krow = kg * 16 + c;
      bf16x8 kf0 = *(const bf16x8*)(kb_ + krow * 64 + ((g ^ (krow & 7)) * 8));
      bf16x8 kf1 = *(const bf16x8*)(kb_ + krow * 64 + (((g + 4) ^ (krow & 7)) * 8));
      #pragma unroll
      for (int qh = 0; qh < 2; ++qh) {
        f32x4 a = {0.f, 0.f, 0.f, 0.f};
        a = __builtin_amdgcn_mfma_f32_16x16x32_bf16(kf0, qf[qh][0], a, 0, 0, 0);
        a = __builtin_amdgcn_mfma_f32_16x16x32_bf16(kf1, qf[qh][1], a, 0, 0, 0);
        S[kg][qh] = a;
      }
    }

    #pragma unroll
    for (int kg = 0; kg < 8; ++kg) {
      float4 f4 = *(const float4*)(&fk[t * 128 + kg * 16 + g * 4]);
      #pragma unroll
      for (int r = 0; r < 4; ++r) {
        float f = (r == 0) ? f4.x : (r == 1) ? f4.y : (r == 2) ? f4.z : f4.w;
        {
          float dd = f - rc0.x, x = f * rc0.x * dd;
          float sel = (dd >= 0.f) ? rc0.z : rc0.w;
          float e = __builtin_amdgcn_exp2f(fmaf(rc0.y, S[kg][0][r], fmaf(x, sel, -sh0)));
          if (kg & 1) ps0a += e; else ps0b += e;
          S[kg][0][r] = e;
        }
        {
          float dd = f - rc1.x, x = f * rc1.x * dd;
          float sel = (dd >= 0.f) ? rc1.z : rc1.w;
          float e = __builtin_amdgcn_exp2f(fmaf(rc1.y, S[kg][1][r], fmaf(x, sel, -sh1)));
          if (kg & 1) ps1a += e; else ps1b += e;
          S[kg][1][r] = e;
        }
      }
    }

    __builtin_amdgcn_s_setprio(1);
    #pragma unroll
    for (int ks = 0; ks < 4; ++ks) {
      union AW { unsigned u[4]; bf16x8 v; } aw0, aw1;
      #pragma unroll
      for (int m = 0; m < 4; ++m) {
        int kg2 = 2 * ks + (m >> 1), rr = (m & 1) * 2;
        unsigned a0 = __float_as_uint(S[kg2][0][rr]), a1 = __float_as_uint(S[kg2][0][rr + 1]);
        aw0.u[m] = ((a1 + 0x8000u) & 0xFFFF0000u) | ((a0 + 0x8000u) >> 16);
        unsigned b0 = __float_as_uint(S[kg2][1][rr]), b1 = __float_as_uint(S[kg2][1][rr + 1]);
        aw1.u[m] = ((b1 + 0x8000u) & 0xFFFF0000u) | ((b0 + 0x8000u) >> 16);
      }
      #pragma unroll
      for (int db = 0; db < 4; ++db) {
        int d = db * 16 + c;
        bf16x8 bv = *(const bf16x8*)(vb_ + d * 128 + (((ks * 4 + g) ^ c) * 8));
        acc[0][db] = __builtin_amdgcn_mfma_f32_16x16x32_bf16(aw0.v, bv, acc[0][db], 0, 0, 0);
        acc[1][db] = __builtin_amdgcn_mfma_f32_16x16x32_bf16(aw1.v, bv, acc[1][db], 0, 0, 0);
      }
    }
    __builtin_amdgcn_s_setprio(0);
  }

  float ps0 = ps0a + ps0b, ps1 = ps1a + ps1b;
  ps0 += __shfl_xor(ps0, 16); ps0 += __shfl_xor(ps0, 32);
  ps1 += __shfl_xor(ps1, 16); ps1 += __shfl_xor(ps1, 32);
  if (g == 0) { psumW[w * 32 + c] = ps0; psumW[w * 32 + 16 + c] = ps1; }

  #pragma unroll
  for (int qh = 0; qh < 2; ++qh)
    #pragma unroll
    for (int r = 0; r < 4; ++r) {
      float rcp = 1.f / psumW[w * 32 + qh * 16 + g * 4 + r];
      int qg = t0 + w * 32 + qh * 16 + g * 4 + r;
      unsigned short* orow = attnO + (size_t)(b * 1024 + qg) * 512 + h * 64 + c;
      #pragma unroll
      for (int db = 0; db < 4; ++db)
        orow[db * 16] = f2bf(acc[qh][db][r] * rcp);
    }
}

extern "C" void kernel_launch(void* const* d_in, const int* in_sizes, int n_in,
                              void* d_out, int out_size, void* d_ws, size_t ws_size,
                              hipStream_t stream) {
  const float* q = (const float*)d_in[0];
  const float* k = (const float*)d_in[1];
  const float* v = (const float*)d_in[2];
  const float* frac = (const float*)d_in[3];
  const float* Wq = (const float*)d_in[4];
  const float* bq = (const float*)d_in[5];
  const float* Wk = (const float*)d_in[6];
  const float* bk = (const float*)d_in[7];
  const float* Wv = (const float*)d_in[8];
  const float* bv = (const float*)d_in[9];
  const float* Wo = (const float*)d_in[10];
  const float* bo = (const float*)d_in[11];
  const float* ap = (const float*)d_in[12];
  const float* an = (const float*)d_in[13];
  const float* gm = (const float*)d_in[14];
  const float* dl = (const float*)d_in[15];
  const int* afb = (const int*)d_in[16];

  char* ws = (char*)d_ws;
  unsigned short* wqT = (unsigned short*)(ws + 0);
  unsigned short* wkT = (unsigned short*)(ws + 524288);
  unsigned short* wvT = (unsigned short*)(ws + 1048576);
  unsigned short* woT = (unsigned short*)(ws + 1572864);
  unsigned short* Qh = (unsigned short*)(ws + 2097152);
  unsigned short* Kh = (unsigned short*)(ws + 10485760);
  unsigned short* Ktr = (unsigned short*)(ws + 18874368);
  unsigned short* Vt = (unsigned short*)(ws + 27262976);
  unsigned short* aO = (unsigned short*)(ws + 35651584);
  float* fst = (float*)(ws + 44040192);
  unsigned short* Mhi = (unsigned short*)(ws + 44171264);
  unsigned short* Mlo = (unsigned short*)(ws + 44695552);
  float* KsumG = (float*)(ws + 45219840);

  hipFuncSetAttribute((const void*)flash_kernel,
                      hipFuncAttributeMaxDynamicSharedMemorySize, FLASH_SMEM);

  prep_kernel<<<3072, 256, 0, stream>>>(Wq, Wk, Wv, Wo, wqT, wkT, wvT, woT, frac, fst);
  qkv_gemm_kernel<<<768, 256, 0, stream>>>(q, k, v, wqT, wkT, wvT,
                                           bq, bk, bv, Qh, Kh, Ktr, Vt);
  gram_kernel<<<64, 256, 0, stream>>>(Ktr, Mhi, Mlo, KsumG);
  flash_kernel<<<512, 256, FLASH_SMEM, stream>>>(Qh, Kh, Vt, aO, frac,
                                                 Mhi, Mlo, KsumG, fst,
                                                 ap, an, gm, dl, afb);
  gemm_out_kernel<<<256, 256, 0, stream>>>(aO, woT, bo, (float*)d_out);
}

// Round 20
// 117.206 us; speedup vs baseline: 1.6005x; 1.0056x over previous
//
#include <hip/hip_runtime.h>
#include <hip/hip_bf16.h>

#define EPS 1e-5f
#define FLASH_SMEM 72704

typedef short bf16x8 __attribute__((ext_vector_type(8)));
typedef float f32x4 __attribute__((ext_vector_type(4)));

#define GL16(gp, lp) __builtin_amdgcn_global_load_lds( \
    (const __attribute__((address_space(1))) void*)(gp), \
    (__attribute__((address_space(3))) void*)(lp), 16, 0, 0)

__device__ __forceinline__ unsigned short f2bf(float f) {
  union { float f; unsigned u; } v; v.f = f;
  return (unsigned short)((v.u + 0x7FFFu + ((v.u >> 16) & 1u)) >> 16);
}
__device__ __forceinline__ float bf2f(unsigned short u) {
  return __uint_as_float(((unsigned)u) << 16);
}

// ---------------- merged prep: 4 weight transposes + frac stats in one launch ----------------
__global__ void prep_kernel(const float* __restrict__ W0, const float* __restrict__ W1,
                            const float* __restrict__ W2, const float* __restrict__ W3,
                            unsigned short* __restrict__ T0, unsigned short* __restrict__ T1,
                            unsigned short* __restrict__ T2, unsigned short* __restrict__ T3,
                            const float* __restrict__ frac, float* __restrict__ fstats) {
  __shared__ float tile[32][33];
  const int L = blockIdx.x;
  if (L < 1024) {
    int z = L >> 8, rem = L & 255;
    const float* W = z == 0 ? W0 : z == 1 ? W1 : z == 2 ? W2 : W3;
    unsigned short* Wt = z == 0 ? T0 : z == 1 ? T1 : z == 2 ? T2 : T3;
    float scale = (z == 0) ? 0.125f : 1.0f;
    int n0 = (rem & 15) * 32, k0 = (rem >> 4) * 32;
    int c = threadIdx.x & 31, r0 = threadIdx.x >> 5;
    #pragma unroll
    for (int rr = 0; rr < 32; rr += 8)
      tile[r0 + rr][c] = W[(k0 + r0 + rr) * 512 + n0 + c];
    __syncthreads();
    #pragma unroll
    for (int rr = 0; rr < 32; rr += 8)
      Wt[(n0 + r0 + rr) * 512 + k0 + c] = f2bf(tile[c][r0 + rr] * scale);
  } else {
    int wid = (int)(((L - 1024) * 256 + threadIdx.x) >> 6);
    int ln = threadIdx.x & 63;
    int b = wid >> 10, q = wid & 1023;
    const float* fr = frac + b * 1024;
    float fq = fr[q];
    float sp = 0.f, sn = 0.f, sp2 = 0.f, sn2 = 0.f;
    for (int i = ln; i < 1024; i += 64) {
      float f = fr[i];
      float dm = (f - fq) * (fq * f);
      float p = fmaxf(dm, 0.f), nn = fminf(dm, 0.f);
      sp += p; sn += nn; sp2 += p * p; sn2 += nn * nn;
    }
    #pragma unroll
    for (int m = 32; m; m >>= 1) {
      sp += __shfl_xor(sp, m); sn += __shfl_xor(sn, m);
      sp2 += __shfl_xor(sp2, m); sn2 += __shfl_xor(sn2, m);
    }
    if (ln == 0) {
      float4 o; o.x = sp; o.y = sn; o.z = sp2; o.w = sn2;
      *(float4*)(fstats + (size_t)wid * 4) = o;
    }
  }
}

// ---------------- fused QKV GEMM: A staged as fp32 via GL16, cvt on read ----------------
__global__ __launch_bounds__(256) void qkv_gemm_kernel(
    const float* __restrict__ Aq, const float* __restrict__ Ak, const float* __restrict__ Av,
    const unsigned short* __restrict__ WqT, const unsigned short* __restrict__ WkT,
    const unsigned short* __restrict__ WvT,
    const float* __restrict__ bq, const float* __restrict__ bk, const float* __restrict__ bv,
    unsigned short* __restrict__ Qh, unsigned short* __restrict__ Kh,
    unsigned short* __restrict__ Ktr, unsigned short* __restrict__ Vt) {
  __shared__ float AlF[2][128 * 32];
  __shared__ unsigned short Bl[2][128 * 32];
  const int L = blockIdx.x;
  const int xcd = L & 7, sl = L >> 3;
  const int xb = sl & 3;
  const int P = (sl >> 2) * 8 + xcd;
  const int yb = P & 63, z = P >> 6;

  const float* A = z == 0 ? Aq : z == 1 ? Ak : Av;
  const unsigned short* Bt = z == 0 ? WqT : z == 1 ? WkT : WvT;
  const float* bias = z == 0 ? bq : z == 1 ? bk : bv;
  const float bscale = (z == 0) ? 0.125f : 1.0f;

  const int tid = threadIdx.x, ln = tid & 63, wv = tid >> 6;
  const int m0 = yb * 128, n0 = xb * 128;
  const int wr = wv >> 1, wc = wv & 1;

  auto stageA = [&](int kt, int buf) {
    #pragma unroll
    for (int u = 0; u < 4; ++u) {
      int n = tid + u * 256;
      int row = n >> 3, ch = n & 7;
      GL16(A + (size_t)(m0 + row) * 512 + kt * 32 + ((ch ^ (row & 7)) * 4),
           &AlF[buf][n * 4]);
    }
  };
  auto stageB = [&](int kt, int buf) {
    int kb = kt * 32;
    #pragma unroll
    for (int u = 0; u < 2; ++u) {
      int n = tid + u * 256;
      int Lrow = n >> 2, kcs = n & 3;
      int kc = kcs ^ (Lrow & 3);
      GL16(Bt + (size_t)(n0 + Lrow) * 512 + kb + kc * 8, &Bl[buf][n * 8]);
    }
  };

  f32x4 acc[4][4] = {};
  stageA(0, 0);
  stageB(0, 0);
  for (int kt = 0; kt < 16; ++kt) {
    __syncthreads();
    if (kt < 15) { stageA(kt + 1, (kt + 1) & 1); stageB(kt + 1, (kt + 1) & 1); }
    const float* a_ = AlF[kt & 1];
    const unsigned short* b_ = Bl[kt & 1];
    const int g = ln >> 4;
    bf16x8 afr[4], bfr[4];
    #pragma unroll
    for (int m = 0; m < 4; ++m) {
      int r = wr * 64 + m * 16 + (ln & 15);
      const float* ar = a_ + r * 32;
      float4 fA = *(const float4*)(ar + (((2 * g) ^ (r & 7)) * 4));
      float4 fB = *(const float4*)(ar + (((2 * g + 1) ^ (r & 7)) * 4));
      union { unsigned u[4]; bf16x8 v; } cv;
      asm("v_cvt_pk_bf16_f32 %0, %1, %2" : "=v"(cv.u[0]) : "v"(fA.x), "v"(fA.y));
      asm("v_cvt_pk_bf16_f32 %0, %1, %2" : "=v"(cv.u[1]) : "v"(fA.z), "v"(fA.w));
      asm("v_cvt_pk_bf16_f32 %0, %1, %2" : "=v"(cv.u[2]) : "v"(fB.x), "v"(fB.y));
      asm("v_cvt_pk_bf16_f32 %0, %1, %2" : "=v"(cv.u[3]) : "v"(fB.z), "v"(fB.w));
      afr[m] = cv.v;
    }
    #pragma unroll
    for (int n = 0; n < 4; ++n) {
      int r = wc * 64 + n * 16 + (ln & 15);
      bfr[n] = *(const bf16x8*)(b_ + r * 32 + ((g ^ (r & 3)) * 8));
    }
    #pragma unroll
    for (int m = 0; m < 4; ++m)
      #pragma unroll
      for (int n = 0; n < 4; ++n)
        acc[m][n] = __builtin_amdgcn_mfma_f32_16x16x32_bf16(afr[m], bfr[n], acc[m][n], 0, 0, 0);
  }

  #pragma unroll
  for (int m = 0; m < 4; ++m) {
    #pragma unroll
    for (int n = 0; n < 4; ++n) {
      int gm0 = m0 + wr * 64 + m * 16 + (ln >> 4) * 4;
      int gn = n0 + wc * 64 + n * 16 + (ln & 15);
      float bvv = bias[gn] * bscale;
      int hh = gn >> 6, d = gn & 63;
      if (z < 2) {
        unsigned short* o = z == 0 ? Qh : Kh;
        #pragma unroll
        for (int i = 0; i < 4; ++i) {
          int gm = gm0 + i;
          int bb = gm >> 10, t = gm & 1023;
          o[(size_t)((bb * 8 + hh) * 1024 + t) * 64 + d] = f2bf(acc[m][n][i] + bvv);
        }
        if (z == 1) {
          int bb = gm0 >> 10, t = gm0 & 1023;
          ushort4 pk;
          pk.x = f2bf(acc[m][n][0] + bvv);
          pk.y = f2bf(acc[m][n][1] + bvv);
          pk.z = f2bf(acc[m][n][2] + bvv);
          pk.w = f2bf(acc[m][n][3] + bvv);
          *(ushort4*)(Ktr + (size_t)((bb * 8 + hh) * 64 + d) * 1024 + t) = pk;
        }
      } else {
        int bb = gm0 >> 10, t = gm0 & 1023;
        int k5 = t & 31;
        int pos = (t & ~31) + ((k5 >> 2) & 3) * 8 + ((k5 >> 4) & 1) * 4;
        ushort4 pk;
        pk.x = f2bf(acc[m][n][0] + bvv);
        pk.y = f2bf(acc[m][n][1] + bvv);
        pk.z = f2bf(acc[m][n][2] + bvv);
        pk.w = f2bf(acc[m][n][3] + bvv);
        *(ushort4*)(Vt + (size_t)((bb * 8 + hh) * 64 + d) * 1024 + pos) = pk;
      }
    }
  }
}

// ---------------- final GEMM (XCD-panel-swizzled grid) ----------------
__global__ __launch_bounds__(256) void gemm_out_kernel(
    const unsigned short* __restrict__ A,
    const unsigned short* __restrict__ Bt,
    const float* __restrict__ bias,
    float* __restrict__ out) {
  __shared__ unsigned short Al[2][128 * 32];
  __shared__ unsigned short Bl[2][128 * 32];
  const int L = blockIdx.x;
  const int xcd = L & 7, sl = L >> 3;
  const int xb = sl & 3, yb = (sl >> 2) * 8 + xcd;
  const int tid = threadIdx.x, ln = tid & 63, wv = tid >> 6;
  const int m0 = yb * 128, n0 = xb * 128;
  const int wr = wv >> 1, wc = wv & 1;

  auto stage = [&](int kt, int buf) {
    int kb = kt * 32;
    #pragma unroll
    for (int u = 0; u < 2; ++u) {
      int n = tid + u * 256;
      int Lrow = n >> 2, kcs = n & 3;
      int kc = kcs ^ (Lrow & 3);
      GL16(A + (size_t)(m0 + Lrow) * 512 + kb + kc * 8, &Al[buf][n * 8]);
      GL16(Bt + (size_t)(n0 + Lrow) * 512 + kb + kc * 8, &Bl[buf][n * 8]);
    }
  };

  f32x4 acc[4][4] = {};
  stage(0, 0);
  for (int kt = 0; kt < 16; ++kt) {
    __syncthreads();
    if (kt < 15) stage(kt + 1, (kt + 1) & 1);
    const unsigned short* a_ = Al[kt & 1];
    const unsigned short* b_ = Bl[kt & 1];
    const int kc = ln >> 4;
    bf16x8 afr[4], bfr[4];
    #pragma unroll
    for (int m = 0; m < 4; ++m) {
      int r = wr * 64 + m * 16 + (ln & 15);
      afr[m] = *(const bf16x8*)(a_ + r * 32 + ((kc ^ (r & 3)) * 8));
    }
    #pragma unroll
    for (int n = 0; n < 4; ++n) {
      int r = wc * 64 + n * 16 + (ln & 15);
      bfr[n] = *(const bf16x8*)(b_ + r * 32 + ((kc ^ (r & 3)) * 8));
    }
    #pragma unroll
    for (int m = 0; m < 4; ++m)
      #pragma unroll
      for (int n = 0; n < 4; ++n)
        acc[m][n] = __builtin_amdgcn_mfma_f32_16x16x32_bf16(afr[m], bfr[n], acc[m][n], 0, 0, 0);
  }
  #pragma unroll
  for (int m = 0; m < 4; ++m)
    #pragma unroll
    for (int n = 0; n < 4; ++n) {
      int gm0 = m0 + wr * 64 + m * 16 + (ln >> 4) * 4;
      int gn = n0 + wc * 64 + n * 16 + (ln & 15);
      float bvv = bias[gn];
      #pragma unroll
      for (int i = 0; i < 4; ++i)
        out[(size_t)(gm0 + i) * 512 + gn] = acc[m][n][i] + bvv;
    }
}

// ---------------- Gram: M = K^T K split bf16 hi/lo + Ksum per (b,h) ----------------
__global__ __launch_bounds__(256, 1) void gram_kernel(
    const unsigned short* __restrict__ Ktr,
    unsigned short* __restrict__ Mhi, unsigned short* __restrict__ Mlo,
    float* __restrict__ KsumG) {
  __shared__ float KsR[4][64];
  const int bh = blockIdx.x;
  const unsigned short* Kb = Ktr + (size_t)bh * 65536;
  const int tid = threadIdx.x, ln = tid & 63, w = tid >> 6;
  const int c = ln & 15, g = ln >> 4;

  f32x4 acc[4] = {};
  #pragma unroll 2
  for (int kk = 0; kk < 32; ++kk) {
    bf16x8 af = *(const bf16x8*)(Kb + (size_t)(w * 16 + c) * 1024 + kk * 32 + g * 8);
    #pragma unroll
    for (int jt = 0; jt < 4; ++jt) {
      bf16x8 bf = *(const bf16x8*)(Kb + (size_t)(jt * 16 + c) * 1024 + kk * 32 + g * 8);
      acc[jt] = __builtin_amdgcn_mfma_f32_16x16x32_bf16(af, bf, acc[jt], 0, 0, 0);
    }
  }
  #pragma unroll
  for (int jt = 0; jt < 4; ++jt)
    #pragma unroll
    for (int r = 0; r < 4; ++r) {
      float v = acc[jt][r];
      unsigned short hi = f2bf(v);
      unsigned short lo = f2bf(v - bf2f(hi));
      size_t idx = (size_t)bh * 4096 + (w * 16 + g * 4 + r) * 64 + jt * 16 + c;
      Mhi[idx] = hi;
      Mlo[idx] = lo;
    }

  int d = tid & 63, seg = tid >> 6;
  float s = 0.f;
  for (int u = 0; u < 32; ++u) {
    bf16x8 v8 = *(const bf16x8*)(Kb + (size_t)d * 1024 + seg * 256 + u * 8);
    #pragma unroll
    for (int e = 0; e < 8; ++e) s += bf2f((unsigned short)v8[e]);
  }
  KsR[seg][d] = s;
  __syncthreads();
  if (tid < 64)
    KsumG[bh * 64 + tid] = KsR[0][tid] + KsR[1][tid] + KsR[2][tid] + KsR[3][tid];
}

// ---------------- flash with fused coef: (bh,128q)/block, 4 waves x 32q ----------------
__global__ __launch_bounds__(256, 2) void flash_kernel(
    const unsigned short* __restrict__ Qh,
    const unsigned short* __restrict__ Kh,
    const unsigned short* __restrict__ Vt,
    unsigned short* __restrict__ attnO,
    const float* __restrict__ frac,
    const unsigned short* __restrict__ Mhi, const unsigned short* __restrict__ Mlo,
    const float* __restrict__ KsumG, const float* __restrict__ fstats,
    const float* __restrict__ alpha_pos, const float* __restrict__ alpha_neg,
    const float* __restrict__ gamma_p, const float* __restrict__ delta_p,
    const int* __restrict__ afb_p) {
  extern __shared__ char smem[];
  unsigned short* Kl = (unsigned short*)smem;
  unsigned short* Vl = (unsigned short*)(smem + 32768);
  float* fk = (float*)(smem + 65536);
  float4* rowcS = (float4*)(smem + 69632);
  float* rowShS = (float*)(smem + 71680);
  float* psumW = (float*)(smem + 72192);

  const int L = blockIdx.x;
  const int xcd = L & 7, s = L >> 3;
  const int bh = xcd + 8 * (s >> 3);
  const int t0 = (s & 7) * 128;
  const int b = bh >> 3, h = bh & 7;
  const int tid = threadIdx.x, ln = tid & 63, w = tid >> 6;
  const int c = ln & 15, g = ln >> 4;

  auto stageK = [&](int t, int buf) {
    #pragma unroll
    for (int u = 0; u < 4; ++u) {
      int n = tid + u * 256;
      int row = n >> 3, kc = (n & 7) ^ (row & 7);
      GL16(Kh + (size_t)(bh * 1024 + t * 128 + row) * 64 + kc * 8,
           Kl + buf * 8192 + n * 8);
    }
  };
  auto stageV = [&](int t, int buf) {
    #pragma unroll
    for (int u = 0; u < 4; ++u) {
      int n = tid + u * 256;
      int d = n >> 4, ch = n & 15;
      GL16(Vt + (size_t)(bh * 64 + d) * 1024 + t * 128 + (ch ^ (d & 15)) * 8,
           Vl + buf * 8192 + n * 8);
    }
  };

  stageK(0, 0);
  stageV(0, 0);
  GL16(frac + b * 1024 + tid * 4, fk + tid * 4);

  bf16x8 qf[2][2];
  #pragma unroll
  for (int qh = 0; qh < 2; ++qh) {
    const unsigned short* qrow =
        Qh + (size_t)(bh * 1024 + t0 + w * 32 + qh * 16 + c) * 64 + g * 8;
    qf[qh][0] = *(const bf16x8*)(qrow);
    qf[qh][1] = *(const bf16x8*)(qrow + 32);
  }

  // ---- fused coef: this block's 128 rows, 2 passes/wave; qf IS the A-fragment ----
  {
    const float gmv = *gamma_p, dlv = *delta_p;
    const float apv = alpha_pos[h], anv = alpha_neg[h];
    const int afb = *afb_p;
    const float L2E = 1.4426950408889634f;
    const unsigned short* Mh = Mhi + (size_t)bh * 4096;
    const unsigned short* Ml = Mlo + (size_t)bh * 4096;
    float ks[4];
    #pragma unroll
    for (int jt = 0; jt < 4; ++jt) ks[jt] = KsumG[bh * 64 + jt * 16 + c];

    #pragma unroll
    for (int pass = 0; pass < 2; ++pass) {
      const int qrow0 = t0 + w * 32 + pass * 16;
      f32x4 acy[4] = {};
      #pragma unroll
      for (int jt = 0; jt < 4; ++jt) {
        const unsigned short* mrow = Mh + (jt * 16 + c) * 64 + g * 8;
        const unsigned short* lrow = Ml + (jt * 16 + c) * 64 + g * 8;
        bf16x8 mh0 = *(const bf16x8*)(mrow);
        bf16x8 mh1 = *(const bf16x8*)(mrow + 32);
        bf16x8 ml0 = *(const bf16x8*)(lrow);
        bf16x8 ml1 = *(const bf16x8*)(lrow + 32);
        acy[jt] = __builtin_amdgcn_mfma_f32_16x16x32_bf16(qf[pass][0], mh0, acy[jt], 0, 0, 0);
        acy[jt] = __builtin_amdgcn_mfma_f32_16x16x32_bf16(qf[pass][1], mh1, acy[jt], 0, 0, 0);
        acy[jt] = __builtin_amdgcn_mfma_f32_16x16x32_bf16(qf[pass][0], ml0, acy[jt], 0, 0, 0);
        acy[jt] = __builtin_amdgcn_mfma_f32_16x16x32_bf16(qf[pass][1], ml1, acy[jt], 0, 0, 0);
      }
      float pl[4], p2[4];
      #pragma unroll
      for (int r = 0; r < 4; ++r) {
        const unsigned short* qd = Qh + (size_t)(bh * 1024 + qrow0 + g * 4 + r) * 64 + c;
        float l = 0.f, s2 = 0.f;
        #pragma unroll
        for (int jt = 0; jt < 4; ++jt) {
          float qv = bf2f(qd[jt * 16]);
          s2 += qv * acy[jt][r];
          l += qv * ks[jt];
        }
        pl[r] = l; p2[r] = s2;
      }
      #pragma unroll
      for (int m = 1; m < 16; m <<= 1)
        #pragma unroll
        for (int r = 0; r < 4; ++r) {
          pl[r] += __shfl_xor(pl[r], m);
          p2[r] += __shfl_xor(p2[r], m);
        }
      if (c == 0) {
        #pragma unroll
        for (int r = 0; r < 4; ++r) {
          int q = qrow0 + g * 4 + r;
          int lq = w * 32 + pass * 16 + g * 4 + r;
          float sl = pl[r], sl2 = p2[r];
          float mul_ = sl * (1.f / 1024.f);
          float varl = fmaxf((sl2 - 1024.f * mul_ * mul_) * (1.f / 1023.f), 0.f);
          float cA = gmv / (sqrtf(varl) + EPS);
          float4 st = *(const float4*)(fstats + (size_t)(b * 1024 + q) * 4);
          float msum = apv * st.x + anv * st.y;
          float msq = apv * apv * st.z + anv * anv * st.w;
          float mus = msum * (1.f / 1024.f);
          float vars = fmaxf((msq - 1024.f * mus * mus) * (1.f / 1023.f), 0.f);
          float cB = afb ? (dlv / (sqrtf(vars) + EPS)) : 0.f;
          float4 rc;
          rc.x = frac[b * 1024 + q];
          rc.y = cA * L2E;
          rc.z = cB * apv * L2E;
          rc.w = cB * anv * L2E;
          rowcS[lq] = rc;
          rowShS[lq] = (cA * mul_ + cB * mus) * L2E;
        }
      }
    }
  }
  __syncthreads();

  const float4 rc0 = rowcS[w * 32 + c], rc1 = rowcS[w * 32 + 16 + c];
  const float sh0 = rowShS[w * 32 + c], sh1 = rowShS[w * 32 + 16 + c];

  f32x4 acc[2][4] = {};
  float ps0a = 0.f, ps0b = 0.f, ps1a = 0.f, ps1b = 0.f;

  for (int t = 0; t < 8; ++t) {
    if (t) __syncthreads();
    if (t < 7) { stageK(t + 1, (t + 1) & 1); stageV(t + 1, (t + 1) & 1); }
    const unsigned short* kb_ = Kl + (t & 1) * 8192;
    const unsigned short* vb_ = Vl + (t & 1) * 8192;

    f32x4 S[8][2];
    #pragma unroll
    for (int kg = 0; kg < 8; ++kg) {
      int krow = kg * 16 + c;
      bf16x8 kf0 = *(const bf16x8*)(kb_ + krow * 64 + ((g ^ (krow & 7)) * 8));
      bf16x8 kf1 = *(const bf16x8*)(kb_ + krow * 64 + (((g + 4) ^ (krow & 7)) * 8));
      #pragma unroll
      for (int qh = 0; qh < 2; ++qh) {
        f32x4 a = {0.f, 0.f, 0.f, 0.f};
        a = __builtin_amdgcn_mfma_f32_16x16x32_bf16(kf0, qf[qh][0], a, 0, 0, 0);
        a = __builtin_amdgcn_mfma_f32_16x16x32_bf16(kf1, qf[qh][1], a, 0, 0, 0);
        S[kg][qh] = a;
      }
    }

    #pragma unroll
    for (int kg = 0; kg < 8; ++kg) {
      float4 f4 = *(const float4*)(&fk[t * 128 + kg * 16 + g * 4]);
      #pragma unroll
      for (int r = 0; r < 4; ++r) {
        float f = (r == 0) ? f4.x : (r == 1) ? f4.y : (r == 2) ? f4.z : f4.w;
        {
          float dd = f - rc0.x, x = f * rc0.x * dd;
          float sel = (dd >= 0.f) ? rc0.z : rc0.w;
          float e = __builtin_amdgcn_exp2f(fmaf(rc0.y, S[kg][0][r], fmaf(x, sel, -sh0)));
          if (kg & 1) ps0a += e; else ps0b += e;
          S[kg][0][r] = e;
        }
        {
          float dd = f - rc1.x, x = f * rc1.x * dd;
          float sel = (dd >= 0.f) ? rc1.z : rc1.w;
          float e = __builtin_amdgcn_exp2f(fmaf(rc1.y, S[kg][1][r], fmaf(x, sel, -sh1)));
          if (kg & 1) ps1a += e; else ps1b += e;
          S[kg][1][r] = e;
        }
      }
    }

    __builtin_amdgcn_s_setprio(1);
    #pragma unroll
    for (int ks = 0; ks < 4; ++ks) {
      union AW { unsigned u[4]; bf16x8 v; } aw0, aw1;
      #pragma unroll
      for (int m = 0; m < 4; ++m) {
        int kg2 = 2 * ks + (m >> 1), rr = (m & 1) * 2;
        asm("v_cvt_pk_bf16_f32 %0, %1, %2"
            : "=v"(aw0.u[m]) : "v"(S[kg2][0][rr]), "v"(S[kg2][0][rr + 1]));
        asm("v_cvt_pk_bf16_f32 %0, %1, %2"
            : "=v"(aw1.u[m]) : "v"(S[kg2][1][rr]), "v"(S[kg2][1][rr + 1]));
      }
      #pragma unroll
      for (int db = 0; db < 4; ++db) {
        int d = db * 16 + c;
        bf16x8 bv = *(const bf16x8*)(vb_ + d * 128 + (((ks * 4 + g) ^ c) * 8));
        acc[0][db] = __builtin_amdgcn_mfma_f32_16x16x32_bf16(aw0.v, bv, acc[0][db], 0, 0, 0);
        acc[1][db] = __builtin_amdgcn_mfma_f32_16x16x32_bf16(aw1.v, bv, acc[1][db], 0, 0, 0);
      }
    }
    __builtin_amdgcn_s_setprio(0);
  }

  float ps0 = ps0a + ps0b, ps1 = ps1a + ps1b;
  ps0 += __shfl_xor(ps0, 16); ps0 += __shfl_xor(ps0, 32);
  ps1 += __shfl_xor(ps1, 16); ps1 += __shfl_xor(ps1, 32);
  if (g == 0) { psumW[w * 32 + c] = ps0; psumW[w * 32 + 16 + c] = ps1; }

  #pragma unroll
  for (int qh = 0; qh < 2; ++qh)
    #pragma unroll
    for (int r = 0; r < 4; ++r) {
      float rcp = 1.f / psumW[w * 32 + qh * 16 + g * 4 + r];
      int qg = t0 + w * 32 + qh * 16 + g * 4 + r;
      unsigned short* orow = attnO + (size_t)(b * 1024 + qg) * 512 + h * 64 + c;
      #pragma unroll
      for (int db = 0; db < 4; ++db)
        orow[db * 16] = f2bf(acc[qh][db][r] * rcp);
    }
}

extern "C" void kernel_launch(void* const* d_in, const int* in_sizes, int n_in,
                              void* d_out, int out_size, void* d_ws, size_t ws_size,
                              hipStream_t stream) {
  const float* q = (const float*)d_in[0];
  const float* k = (const float*)d_in[1];
  const float* v = (const float*)d_in[2];
  const float* frac = (const float*)d_in[3];
  const float* Wq = (const float*)d_in[4];
  const float* bq = (const float*)d_in[5];
  const float* Wk = (const float*)d_in[6];
  const float* bk = (const float*)d_in[7];
  const float* Wv = (const float*)d_in[8];
  const float* bv = (const float*)d_in[9];
  const float* Wo = (const float*)d_in[10];
  const float* bo = (const float*)d_in[11];
  const float* ap = (const float*)d_in[12];
  const float* an = (const float*)d_in[13];
  const float* gm = (const float*)d_in[14];
  const float* dl = (const float*)d_in[15];
  const int* afb = (const int*)d_in[16];

  char* ws = (char*)d_ws;
  unsigned short* wqT = (unsigned short*)(ws + 0);
  unsigned short* wkT = (unsigned short*)(ws + 524288);
  unsigned short* wvT = (unsigned short*)(ws + 1048576);
  unsigned short* woT = (unsigned short*)(ws + 1572864);
  unsigned short* Qh = (unsigned short*)(ws + 2097152);
  unsigned short* Kh = (unsigned short*)(ws + 10485760);
  unsigned short* Ktr = (unsigned short*)(ws + 18874368);
  unsigned short* Vt = (unsigned short*)(ws + 27262976);
  unsigned short* aO = (unsigned short*)(ws + 35651584);
  float* fst = (float*)(ws + 44040192);
  unsigned short* Mhi = (unsigned short*)(ws + 44171264);
  unsigned short* Mlo = (unsigned short*)(ws + 44695552);
  float* KsumG = (float*)(ws + 45219840);

  hipFuncSetAttribute((const void*)flash_kernel,
                      hipFuncAttributeMaxDynamicSharedMemorySize, FLASH_SMEM);

  prep_kernel<<<3072, 256, 0, stream>>>(Wq, Wk, Wv, Wo, wqT, wkT, wvT, woT, frac, fst);
  qkv_gemm_kernel<<<768, 256, 0, stream>>>(q, k, v, wqT, wkT, wvT,
                                           bq, bk, bv, Qh, Kh, Ktr, Vt);
  gram_kernel<<<64, 256, 0, stream>>>(Ktr, Mhi, Mlo, KsumG);
  flash_kernel<<<512, 256, FLASH_SMEM, stream>>>(Qh, Kh, Vt, aO, frac,
                                                 Mhi, Mlo, KsumG, fst,
                                                 ap, an, gm, dl, afb);
  gemm_out_kernel<<<256, 256, 0, stream>>>(aO, woT, bo, (float*)d_out);
}